// Round 1
// baseline (991.855 us; speedup 1.0000x reference)
//
#include <hip/hip_runtime.h>
#include <math.h>

#define NNODES 50000
#define NEDGES 500000
#define HID 128
#define NCLS 40

// ---------------------------------------------------------------------------
// row_ptr build from sorted COO row array: rp[q] = first edge e with row[e]>=q
// ---------------------------------------------------------------------------
static __global__ void build_rowptr_kernel(const int* __restrict__ row, int E, int N,
                                           int* __restrict__ rp) {
    int e = blockIdx.x * blockDim.x + threadIdx.x;
    if (e >= E) return;
    int r = row[e];
    int prev = (e == 0) ? -1 : row[e - 1];
    for (int q = prev + 1; q <= r; ++q) rp[q] = e;
    if (e == E - 1) {
        for (int q = r + 1; q <= N; ++q) rp[q] = E;
    }
}

// ---------------------------------------------------------------------------
// SpMM: out[n,f] = sum_{e in [rp[n],rp[n+1])} val[e] * x[ idmap?idmap[col[e]]:col[e], f ]
// block = node, thread = feature (128). Coalesced 512B row gathers.
// ---------------------------------------------------------------------------
static __global__ __launch_bounds__(HID) void spmm_kernel(
    const float* __restrict__ x, const int* __restrict__ col,
    const float* __restrict__ val, const int* __restrict__ rp,
    const int* __restrict__ idmap, float* __restrict__ out) {
    int n = blockIdx.x;
    int f = threadIdx.x;
    int e0 = rp[n], e1 = rp[n + 1];
    float acc = 0.f;
    for (int e = e0; e < e1; ++e) {
        int c = col[e];
        if (idmap) c = idmap[c];
        acc = fmaf(val[e], x[(size_t)c * HID + f], acc);
    }
    out[(size_t)n * HID + f] = acc;
}

// ---------------------------------------------------------------------------
// GEMM helpers. Block tile: 32 rows x 128 cols, 256 threads, each thread 4x4.
// A tile staged transposed in LDS (AsT[k][r], pad 36 keeps 16B align for b128
// reads: 36*4=144B). W read from global (L1/L2 resident, 64KB per matrix).
// ---------------------------------------------------------------------------
#define FMA16(a, w, ACC)                                                        \
    ACC[0][0]=fmaf(a.x,w.x,ACC[0][0]); ACC[0][1]=fmaf(a.x,w.y,ACC[0][1]);       \
    ACC[0][2]=fmaf(a.x,w.z,ACC[0][2]); ACC[0][3]=fmaf(a.x,w.w,ACC[0][3]);       \
    ACC[1][0]=fmaf(a.y,w.x,ACC[1][0]); ACC[1][1]=fmaf(a.y,w.y,ACC[1][1]);       \
    ACC[1][2]=fmaf(a.y,w.z,ACC[1][2]); ACC[1][3]=fmaf(a.y,w.w,ACC[1][3]);       \
    ACC[2][0]=fmaf(a.z,w.x,ACC[2][0]); ACC[2][1]=fmaf(a.z,w.y,ACC[2][1]);       \
    ACC[2][2]=fmaf(a.z,w.z,ACC[2][2]); ACC[2][3]=fmaf(a.z,w.w,ACC[2][3]);       \
    ACC[3][0]=fmaf(a.w,w.x,ACC[3][0]); ACC[3][1]=fmaf(a.w,w.y,ACC[3][1]);       \
    ACC[3][2]=fmaf(a.w,w.z,ACC[3][2]); ACC[3][3]=fmaf(a.w,w.w,ACC[3][3]);

#define STAGE_A(Ap)                                                             \
    do {                                                                        \
        __syncthreads();                                                        \
        _Pragma("unroll")                                                       \
        for (int i = 0; i < 16; ++i) {                                          \
            int idx = tid + i * 256;                                            \
            int r2 = idx >> 7, k2 = idx & 127;                                  \
            int gr = gr0 + r2;                                                  \
            AsT[k2][r2] = (gr < nrows) ? (Ap)[(size_t)gr * HID + k2] : 0.f;     \
        }                                                                       \
        __syncthreads();                                                        \
    } while (0)

#define KLOOP(Wp, ACC)                                                          \
    do {                                                                        \
        _Pragma("unroll 4")                                                     \
        for (int k = 0; k < HID; ++k) {                                         \
            const float4 a = *(const float4*)&AsT[k][rb];                       \
            const float4 w = *(const float4*)&(Wp)[k * HID + cb];               \
            FMA16(a, w, ACC)                                                    \
        }                                                                       \
    } while (0)

// out = relu(Aagg @ Wl + Xdst @ Wr + b)
static __global__ __launch_bounds__(256) void sage_gemm_kernel(
    const float* __restrict__ Aagg, const float* __restrict__ Xdst,
    const float* __restrict__ Wl, const float* __restrict__ Wr,
    const float* __restrict__ bias, float* __restrict__ out, int nrows) {
    __shared__ __align__(16) float AsT[HID][36];
    const int tid = threadIdx.x;
    const int tc = tid & 31, tm = tid >> 5;
    const int cb = tc * 4, rb = tm * 4;
    const int gr0 = blockIdx.x * 32;

    float acc[4][4];
    const float4 bv = *(const float4*)&bias[cb];
#pragma unroll
    for (int m = 0; m < 4; ++m) { acc[m][0] = bv.x; acc[m][1] = bv.y; acc[m][2] = bv.z; acc[m][3] = bv.w; }

    STAGE_A(Aagg);
    KLOOP(Wl, acc);
    STAGE_A(Xdst);
    KLOOP(Wr, acc);

#pragma unroll
    for (int m = 0; m < 4; ++m) {
        int gr = gr0 + rb + m;
        if (gr < nrows) {
            float4 o = make_float4(fmaxf(acc[m][0], 0.f), fmaxf(acc[m][1], 0.f),
                                   fmaxf(acc[m][2], 0.f), fmaxf(acc[m][3], 0.f));
            *(float4*)&out[(size_t)gr * HID + cb] = o;
        }
    }
}

// xm = r*relu(A1@Wl + z) + (1-r)*relu(A2@Wl + z), z = xm@Wr + b   (in place)
static __global__ __launch_bounds__(256) void gemm_mix_kernel(
    const float* __restrict__ A1, const float* __restrict__ A2,
    float* __restrict__ xm,
    const float* __restrict__ Wl, const float* __restrict__ Wr,
    const float* __restrict__ bias, const float* __restrict__ mixr, int nrows) {
    __shared__ __align__(16) float AsT[HID][36];
    const int tid = threadIdx.x;
    const int tc = tid & 31, tm = tid >> 5;
    const int cb = tc * 4, rb = tm * 4;
    const int gr0 = blockIdx.x * 32;

    float acc1[4][4] = {}, acc2[4][4] = {}, accz[4][4];
    const float4 bv = *(const float4*)&bias[cb];
#pragma unroll
    for (int m = 0; m < 4; ++m) { accz[m][0] = bv.x; accz[m][1] = bv.y; accz[m][2] = bv.z; accz[m][3] = bv.w; }

    STAGE_A(A1);
    KLOOP(Wl, acc1);
    STAGE_A(A2);
    KLOOP(Wl, acc2);
    STAGE_A(xm);
    KLOOP(Wr, accz);

    const float r = mixr[0];
#pragma unroll
    for (int m = 0; m < 4; ++m) {
        int gr = gr0 + rb + m;
        if (gr < nrows) {
            float4 o;
            o.x = r * fmaxf(acc1[m][0] + accz[m][0], 0.f) + (1.f - r) * fmaxf(acc2[m][0] + accz[m][0], 0.f);
            o.y = r * fmaxf(acc1[m][1] + accz[m][1], 0.f) + (1.f - r) * fmaxf(acc2[m][1] + accz[m][1], 0.f);
            o.z = r * fmaxf(acc1[m][2] + accz[m][2], 0.f) + (1.f - r) * fmaxf(acc2[m][2] + accz[m][2], 0.f);
            o.w = r * fmaxf(acc1[m][3] + accz[m][3], 0.f) + (1.f - r) * fmaxf(acc2[m][3] + accz[m][3], 0.f);
            *(float4*)&xm[(size_t)gr * HID + cb] = o;
        }
    }
}

// xm = r*x0 + (1-r)*x0[id]   (vectorized gather-mix)
static __global__ void mix_init_kernel(const float4* __restrict__ x0,
                                       const int* __restrict__ id,
                                       const float* __restrict__ mixr,
                                       float4* __restrict__ xm, int n4) {
    int idx = blockIdx.x * blockDim.x + threadIdx.x;
    if (idx >= n4) return;
    int n = idx >> 5, q = idx & 31;
    float r = mixr[0];
    float4 a = x0[idx];
    float4 b = x0[((size_t)id[n] << 5) + q];
    float4 o;
    o.x = r * a.x + (1.f - r) * b.x;
    o.y = r * a.y + (1.f - r) * b.y;
    o.z = r * a.z + (1.f - r) * b.z;
    o.w = r * a.w + (1.f - r) * b.w;
    xm[idx] = o;
}

// logits = xm @ Wout + bout; out = log_softmax(logits). One wave per row.
static __global__ __launch_bounds__(256) void head_kernel(
    const float* __restrict__ xm, const float* __restrict__ Wout,
    const float* __restrict__ bout, float* __restrict__ out) {
    __shared__ float xs[4][HID];
    const int lane = threadIdx.x & 63;
    const int wv = threadIdx.x >> 6;
    const int row = blockIdx.x * 4 + wv;   // N % 4 == 0, always valid
    xs[wv][lane] = xm[(size_t)row * HID + lane];
    xs[wv][lane + 64] = xm[(size_t)row * HID + lane + 64];
    __syncthreads();
    float acc = 0.f;
    if (lane < NCLS) {
        acc = bout[lane];
#pragma unroll 4
        for (int k = 0; k < HID; ++k) acc = fmaf(xs[wv][k], Wout[k * NCLS + lane], acc);
    }
    float v = (lane < NCLS) ? acc : -INFINITY;
#pragma unroll
    for (int off = 32; off > 0; off >>= 1) v = fmaxf(v, __shfl_xor(v, off));
    float ev = (lane < NCLS) ? expf(acc - v) : 0.f;
    float s = ev;
#pragma unroll
    for (int off = 32; off > 0; off >>= 1) s += __shfl_xor(s, off);
    if (lane < NCLS) out[(size_t)row * NCLS + lane] = acc - v - logf(s);
}

// ---------------------------------------------------------------------------
extern "C" void kernel_launch(void* const* d_in, const int* in_sizes, int n_in,
                              void* d_out, int out_size, void* d_ws, size_t ws_size,
                              hipStream_t stream) {
    const float* x0   = (const float*)d_in[0];
    const int*   arow = (const int*)d_in[1];
    const int*   acol = (const int*)d_in[2];
    const float* aval = (const float*)d_in[3];
    const int*   brow = (const int*)d_in[4];
    const int*   bcol = (const int*)d_in[5];
    const float* bval = (const float*)d_in[6];
    const float* mixr = (const float*)d_in[7];
    const int*   id   = (const int*)d_in[8];
    const float* Wl   = (const float*)d_in[9];
    const float* Wr   = (const float*)d_in[10];
    const float* bs   = (const float*)d_in[11];
    const float* Wout = (const float*)d_in[12];
    const float* bout = (const float*)d_in[13];
    float* out = (float*)d_out;

    const int N = NNODES, E = NEDGES;
    const size_t NF = (size_t)N * HID;
    float* ws = (float*)d_ws;
    float* A0 = ws;             // aggrA for layer0 input; reused as aggrA layer2
    float* A1 = ws + NF;        // aggrA for layer1 input
    float* h1 = ws + 2 * NF;
    float* h2 = ws + 3 * NF;
    float* Bb = ws + 4 * NF;    // branch-B aggregation (reused)
    float* xm = ws + 5 * NF;    // x_mix (updated in place)
    int* rpa = (int*)(ws + 6 * NF);
    int* rpb = rpa + (N + 1);

    const dim3 gE((E + 255) / 256);
    build_rowptr_kernel<<<gE, 256, 0, stream>>>(arow, E, N, rpa);
    build_rowptr_kernel<<<gE, 256, 0, stream>>>(brow, E, N, rpb);

    const int gg = (N + 31) / 32;

    // ---- Branch A pre-stack (aggr_xs = {x0, h1, h2}); cache A0, A1 for reuse
    spmm_kernel<<<N, HID, 0, stream>>>(x0, acol, aval, rpa, nullptr, A0);
    sage_gemm_kernel<<<gg, 256, 0, stream>>>(A0, x0, Wl, Wr, bs, h1, N);
    spmm_kernel<<<N, HID, 0, stream>>>(h1, acol, aval, rpa, nullptr, A1);
    sage_gemm_kernel<<<gg, 256, 0, stream>>>(A1, h1, Wl + 16384, Wr + 16384, bs + 128, h2, N);

    // ---- x_mix init
    mix_init_kernel<<<(N * 32 + 255) / 256, 256, 0, stream>>>(
        (const float4*)x0, id, mixr, (float4*)xm, N * 32);

    // ---- Main loop i=0  (A-branch aggregation A0 already cached)
    spmm_kernel<<<N, HID, 0, stream>>>(x0, bcol, bval, rpb, id, Bb);
    gemm_mix_kernel<<<gg, 256, 0, stream>>>(A0, Bb, xm, Wl, Wr, bs, mixr, N);
    // ---- i=1
    spmm_kernel<<<N, HID, 0, stream>>>(h1, bcol, bval, rpb, id, Bb);
    gemm_mix_kernel<<<gg, 256, 0, stream>>>(A1, Bb, xm, Wl + 16384, Wr + 16384, bs + 128, mixr, N);
    // ---- i=2 (need fresh A-branch aggregation of h2)
    spmm_kernel<<<N, HID, 0, stream>>>(h2, acol, aval, rpa, nullptr, A0);
    spmm_kernel<<<N, HID, 0, stream>>>(h2, bcol, bval, rpb, id, Bb);
    gemm_mix_kernel<<<gg, 256, 0, stream>>>(A0, Bb, xm, Wl + 32768, Wr + 32768, bs + 256, mixr, N);

    // ---- Head: logits + log_softmax
    head_kernel<<<N / 4, 256, 0, stream>>>(xm, Wout, bout, out);
}

// Round 2
// 517.947 us; speedup vs baseline: 1.9150x; 1.9150x over previous
//
#include <hip/hip_runtime.h>
#include <math.h>

#define NNODES 50000
#define NEDGES 500000
#define HID 128
#define NCLS 40

using short8v = __attribute__((ext_vector_type(8))) short;
using float4v = __attribute__((ext_vector_type(4))) float;

static __device__ __forceinline__ unsigned short f2bf(float f) {
    unsigned int u = __float_as_uint(f);
    u += 0x7FFFu + ((u >> 16) & 1u);   // RNE
    return (unsigned short)(u >> 16);
}
static __device__ __forceinline__ float bf2f(unsigned short h) {
    return __uint_as_float(((unsigned int)h) << 16);
}

// ---------------------------------------------------------------------------
// row_ptr from sorted COO rows: rp[q] = first e with row[e] >= q
// ---------------------------------------------------------------------------
static __global__ void build_rowptr_kernel(const int* __restrict__ row, int E, int N,
                                           int* __restrict__ rp) {
    int e = blockIdx.x * blockDim.x + threadIdx.x;
    if (e >= E) return;
    int r = row[e];
    int prev = (e == 0) ? -1 : row[e - 1];
    for (int q = prev + 1; q <= r; ++q) rp[q] = e;
    if (e == E - 1) {
        for (int q = r + 1; q <= N; ++q) rp[q] = E;
    }
}

// x0 f32 -> bf16 (thread = 4 elements)
static __global__ void conv_x_kernel(const float4* __restrict__ x, uint2* __restrict__ o) {
    int i = blockIdx.x * blockDim.x + threadIdx.x;   // exactly N*HID/4 threads
    float4 v = x[i];
    uint2 p;
    p.x = (unsigned)f2bf(v.x) | ((unsigned)f2bf(v.y) << 16);
    p.y = (unsigned)f2bf(v.z) | ((unsigned)f2bf(v.w) << 16);
    o[i] = p;
}

// W (L,128,128 row-major [k][n]) -> Wt[mat][n][k] bf16; mats 0-2=Wl, 3-5=Wr
static __global__ void conv_wt_kernel(const float* __restrict__ Wl, const float* __restrict__ Wr,
                                      unsigned short* __restrict__ Wt) {
    int t = blockIdx.x * blockDim.x + threadIdx.x;   // exactly 6*16384 threads
    int mat = t >> 14, idx = t & 16383;
    int n = idx >> 7, k = idx & 127;
    const float* src = (mat < 3) ? (Wl + mat * 16384) : (Wr + (mat - 3) * 16384);
    Wt[t] = f2bf(src[k * HID + n]);
}

// bcol2[e] = id[bcol[e]]
static __global__ void gather_col_kernel(const int* __restrict__ bcol, const int* __restrict__ id,
                                         int* __restrict__ bcol2) {
    int e = blockIdx.x * blockDim.x + threadIdx.x;
    if (e < NEDGES) bcol2[e] = id[bcol[e]];
}

// xm = r*x0 + (1-r)*x0[id], stored bf16
static __global__ void mix_init_kernel(const float4* __restrict__ x, const int* __restrict__ id,
                                       const float* __restrict__ mixr, uint2* __restrict__ o) {
    int i = blockIdx.x * blockDim.x + threadIdx.x;   // N*HID/4 threads
    int n = i >> 5, q = i & 31;
    float r = mixr[0];
    float4 a = x[i];
    float4 b = x[(size_t)id[n] * 32 + q];
    uint2 p;
    p.x = (unsigned)f2bf(r * a.x + (1.f - r) * b.x) |
          ((unsigned)f2bf(r * a.y + (1.f - r) * b.y) << 16);
    p.y = (unsigned)f2bf(r * a.z + (1.f - r) * b.z) |
          ((unsigned)f2bf(r * a.w + (1.f - r) * b.w) << 16);
    o[i] = p;
}

// ---------------------------------------------------------------------------
// SpMM: S[n,:] = sum_e val[e] * y[col[e],:]   (y bf16, S f32). Wave per node,
// lane holds 2 features (bf16x2 = 4B load -> 256B/row gather, coalesced).
// ---------------------------------------------------------------------------
static __global__ __launch_bounds__(256) void spmm_kernel(
    const unsigned short* __restrict__ y, const int* __restrict__ col,
    const float* __restrict__ val, const int* __restrict__ rp,
    float* __restrict__ S) {
    int w = (blockIdx.x * blockDim.x + threadIdx.x) >> 6;   // node (grid covers N exactly)
    int l = threadIdx.x & 63;
    int e0 = rp[w], e1 = rp[w + 1];
    float ax = 0.f, ay = 0.f;
    int e = e0;
    for (; e + 2 <= e1; e += 2) {
        int c0 = col[e], c1 = col[e + 1];
        float v0 = val[e], v1 = val[e + 1];
        unsigned int p0 = *(const unsigned int*)(y + (size_t)c0 * HID + l * 2);
        unsigned int p1 = *(const unsigned int*)(y + (size_t)c1 * HID + l * 2);
        ax = fmaf(v0, __uint_as_float(p0 << 16), ax);
        ay = fmaf(v0, __uint_as_float(p0 & 0xFFFF0000u), ay);
        ax = fmaf(v1, __uint_as_float(p1 << 16), ax);
        ay = fmaf(v1, __uint_as_float(p1 & 0xFFFF0000u), ay);
    }
    if (e < e1) {
        int c0 = col[e];
        float v0 = val[e];
        unsigned int p0 = *(const unsigned int*)(y + (size_t)c0 * HID + l * 2);
        ax = fmaf(v0, __uint_as_float(p0 << 16), ax);
        ay = fmaf(v0, __uint_as_float(p0 & 0xFFFF0000u), ay);
    }
    float2 o = {ax, ay};
    *(float2*)(S + (size_t)w * HID + l * 2) = o;
}

// ---------------------------------------------------------------------------
// MFMA GEMM core: C(64x128 per block) = A(bf16 Nx128) @ Wt^T (Wt is [n][k] bf16).
// 4 waves/block, wave = 16 rows x 128 cols = 8 col-tiles x 4 K-steps of
// mfma_f32_16x16x32_bf16. No LDS. A frag: row=lane&15, k=(lane>>4)*8+j.
// B frag: col=lane&15 (row of Wt), k contiguous. C: col=lane&15, row=(lane>>4)*4+r.
// ---------------------------------------------------------------------------
#define MFMA_CORE(Abuf, Wt)                                                         \
    const int tid = threadIdx.x;                                                    \
    const int lr = tid & 15;                                                        \
    const int lg = (tid >> 4) & 3;                                                  \
    const int r0 = blockIdx.x * 64 + (tid >> 6) * 16;                               \
    float4v acc[8];                                                                 \
    {                                                                               \
        const int arow = min(r0 + lr, NNODES - 1);                                  \
        const unsigned short* ap = (Abuf) + (size_t)arow * HID + lg * 8;            \
        short8v a0 = *(const short8v*)(ap);                                         \
        short8v a1 = *(const short8v*)(ap + 32);                                    \
        short8v a2 = *(const short8v*)(ap + 64);                                    \
        short8v a3 = *(const short8v*)(ap + 96);                                    \
        _Pragma("unroll")                                                           \
        for (int c = 0; c < 8; ++c) {                                               \
            const unsigned short* wp = (Wt) + (size_t)(c * 16 + lr) * HID + lg * 8; \
            short8v b0 = *(const short8v*)(wp);                                     \
            short8v b1 = *(const short8v*)(wp + 32);                                \
            short8v b2 = *(const short8v*)(wp + 64);                                \
            short8v b3 = *(const short8v*)(wp + 96);                                \
            float4v t = {0.f, 0.f, 0.f, 0.f};                                       \
            t = __builtin_amdgcn_mfma_f32_16x16x32_bf16(a0, b0, t, 0, 0, 0);        \
            t = __builtin_amdgcn_mfma_f32_16x16x32_bf16(a1, b1, t, 0, 0, 0);        \
            t = __builtin_amdgcn_mfma_f32_16x16x32_bf16(a2, b2, t, 0, 0, 0);        \
            t = __builtin_amdgcn_mfma_f32_16x16x32_bf16(a3, b3, t, 0, 0, 0);        \
            acc[c] = t;                                                             \
        }                                                                           \
    }

// y = A @ Wl  (bf16 out, no bias)
static __global__ __launch_bounds__(256) void gemm_y_kernel(
    const unsigned short* __restrict__ A, const unsigned short* __restrict__ Wt,
    unsigned short* __restrict__ out) {
    MFMA_CORE(A, Wt)
#pragma unroll
    for (int c = 0; c < 8; ++c) {
#pragma unroll
        for (int r = 0; r < 4; ++r) {
            int m = r0 + lg * 4 + r;
            if (m < NNODES) out[(size_t)m * HID + c * 16 + lr] = f2bf(acc[c][r]);
        }
    }
}

// h = relu(S + A @ Wr + b)  (bf16 out)
static __global__ __launch_bounds__(256) void gemm_h_kernel(
    const unsigned short* __restrict__ A, const unsigned short* __restrict__ Wt,
    const float* __restrict__ S, const float* __restrict__ bias,
    unsigned short* __restrict__ out) {
    MFMA_CORE(A, Wt)
#pragma unroll
    for (int c = 0; c < 8; ++c) {
        float bv = bias[c * 16 + lr];
#pragma unroll
        for (int r = 0; r < 4; ++r) {
            int m = r0 + lg * 4 + r;
            if (m < NNODES) {
                size_t idx = (size_t)m * HID + c * 16 + lr;
                out[idx] = f2bf(fmaxf(acc[c][r] + S[idx] + bv, 0.f));
            }
        }
    }
}

// z = A @ Wr + b; xm = r*relu(S+z) + (1-r)*relu(T+z)  (in-place on xm, bf16)
static __global__ __launch_bounds__(256) void gemm_mix_kernel(
    const unsigned short* A, const unsigned short* __restrict__ Wt,
    const float* __restrict__ S, const float* __restrict__ T,
    const float* __restrict__ bias, const float* __restrict__ mixr,
    unsigned short* out) {
    MFMA_CORE(A, Wt)
    const float rr = mixr[0];
#pragma unroll
    for (int c = 0; c < 8; ++c) {
        float bv = bias[c * 16 + lr];
#pragma unroll
        for (int r = 0; r < 4; ++r) {
            int m = r0 + lg * 4 + r;
            if (m < NNODES) {
                size_t idx = (size_t)m * HID + c * 16 + lr;
                float z = acc[c][r] + bv;
                float xa = fmaxf(S[idx] + z, 0.f);
                float xb = fmaxf(T[idx] + z, 0.f);
                out[idx] = f2bf(rr * xa + (1.f - rr) * xb);
            }
        }
    }
}

// logits = xm @ Wout + bout; log_softmax. Wave per row.
static __global__ __launch_bounds__(256) void head_kernel(
    const unsigned short* __restrict__ xm, const float* __restrict__ Wout,
    const float* __restrict__ bout, float* __restrict__ out) {
    __shared__ float xs[4][HID];
    const int lane = threadIdx.x & 63;
    const int wv = threadIdx.x >> 6;
    const int row = blockIdx.x * 4 + wv;   // N % 4 == 0
    xs[wv][lane] = bf2f(xm[(size_t)row * HID + lane]);
    xs[wv][lane + 64] = bf2f(xm[(size_t)row * HID + lane + 64]);
    __syncthreads();
    float acc = 0.f;
    if (lane < NCLS) {
        acc = bout[lane];
#pragma unroll 4
        for (int k = 0; k < HID; ++k) acc = fmaf(xs[wv][k], Wout[k * NCLS + lane], acc);
    }
    float v = (lane < NCLS) ? acc : -INFINITY;
#pragma unroll
    for (int off = 32; off > 0; off >>= 1) v = fmaxf(v, __shfl_xor(v, off));
    float ev = (lane < NCLS) ? expf(acc - v) : 0.f;
    float s = ev;
#pragma unroll
    for (int off = 32; off > 0; off >>= 1) s += __shfl_xor(s, off);
    if (lane < NCLS) out[(size_t)row * NCLS + lane] = acc - v - logf(s);
}

// ---------------------------------------------------------------------------
extern "C" void kernel_launch(void* const* d_in, const int* in_sizes, int n_in,
                              void* d_out, int out_size, void* d_ws, size_t ws_size,
                              hipStream_t stream) {
    const float* x0   = (const float*)d_in[0];
    const int*   arow = (const int*)d_in[1];
    const int*   acol = (const int*)d_in[2];
    const float* aval = (const float*)d_in[3];
    const int*   brow = (const int*)d_in[4];
    const int*   bcol = (const int*)d_in[5];
    const float* bval = (const float*)d_in[6];
    const float* mixr = (const float*)d_in[7];
    const int*   id   = (const int*)d_in[8];
    const float* Wl   = (const float*)d_in[9];
    const float* Wr   = (const float*)d_in[10];
    const float* bs   = (const float*)d_in[11];
    const float* Wout = (const float*)d_in[12];
    const float* bout = (const float*)d_in[13];
    float* out = (float*)d_out;

    const size_t NF = (size_t)NNODES * HID;   // 6.4M
    unsigned short* x0b = (unsigned short*)d_ws;
    unsigned short* xmb = x0b + NF;
    unsigned short* h1b = xmb + NF;
    unsigned short* h2b = h1b + NF;
    unsigned short* yb  = h2b + NF;
    unsigned short* Wt  = yb + NF;            // 6 * 16384 bf16
    float* S = (float*)(Wt + 6 * 16384);
    float* T = S + NF;
    int* rpa = (int*)(T + NF);
    int* rpb = rpa + (NNODES + 1);
    int* bcol2 = rpb + (NNODES + 1);

    const int gE = (NEDGES + 255) / 256;      // 1954
    const int gC = NNODES * HID / 4 / 256;    // 6250
    const int gG = (NNODES + 63) / 64;        // 782
    const int gS = NNODES * 64 / 256;         // 12500

    build_rowptr_kernel<<<gE, 256, 0, stream>>>(arow, NEDGES, NNODES, rpa);
    build_rowptr_kernel<<<gE, 256, 0, stream>>>(brow, NEDGES, NNODES, rpb);
    conv_x_kernel<<<gC, 256, 0, stream>>>((const float4*)x0, (uint2*)x0b);
    conv_wt_kernel<<<6 * 16384 / 256, 256, 0, stream>>>(Wl, Wr, Wt);
    gather_col_kernel<<<gE, 256, 0, stream>>>(bcol, id, bcol2);
    mix_init_kernel<<<gC, 256, 0, stream>>>((const float4*)x0, id, mixr, (uint2*)xmb);

    // ---- layer 0 (aggr_xs[0] = x0)
    gemm_y_kernel<<<gG, 256, 0, stream>>>(x0b, Wt + 0 * 16384, yb);
    spmm_kernel<<<gS, 256, 0, stream>>>(yb, acol, aval, rpa, S);
    spmm_kernel<<<gS, 256, 0, stream>>>(yb, bcol2, bval, rpb, T);
    gemm_h_kernel<<<gG, 256, 0, stream>>>(x0b, Wt + 3 * 16384, S, bs, h1b);
    gemm_mix_kernel<<<gG, 256, 0, stream>>>(xmb, Wt + 3 * 16384, S, T, bs, mixr, xmb);

    // ---- layer 1 (aggr_xs[1] = h1)
    gemm_y_kernel<<<gG, 256, 0, stream>>>(h1b, Wt + 1 * 16384, yb);
    spmm_kernel<<<gS, 256, 0, stream>>>(yb, acol, aval, rpa, S);
    spmm_kernel<<<gS, 256, 0, stream>>>(yb, bcol2, bval, rpb, T);
    gemm_h_kernel<<<gG, 256, 0, stream>>>(h1b, Wt + 4 * 16384, S, bs + 128, h2b);
    gemm_mix_kernel<<<gG, 256, 0, stream>>>(xmb, Wt + 4 * 16384, S, T, bs + 128, mixr, xmb);

    // ---- layer 2 (aggr_xs[2] = h2)
    gemm_y_kernel<<<gG, 256, 0, stream>>>(h2b, Wt + 2 * 16384, yb);
    spmm_kernel<<<gS, 256, 0, stream>>>(yb, acol, aval, rpa, S);
    spmm_kernel<<<gS, 256, 0, stream>>>(yb, bcol2, bval, rpb, T);
    gemm_mix_kernel<<<gG, 256, 0, stream>>>(xmb, Wt + 5 * 16384, S, T, bs + 256, mixr, xmb);

    head_kernel<<<NNODES / 4, 256, 0, stream>>>(xmb, Wout, bout, out);
}

// Round 3
// 397.863 us; speedup vs baseline: 2.4930x; 1.3018x over previous
//
#include <hip/hip_runtime.h>
#include <math.h>

#define NNODES 50000
#define NEDGES 500000
#define HID 128
#define NCLS 40

using short8v = __attribute__((ext_vector_type(8))) short;
using float4v = __attribute__((ext_vector_type(4))) float;

static __device__ __forceinline__ unsigned short f2bf(float f) {
    unsigned int u = __float_as_uint(f);
    u += 0x7FFFu + ((u >> 16) & 1u);   // RNE
    return (unsigned short)(u >> 16);
}
static __device__ __forceinline__ float bf2f(unsigned short h) {
    return __uint_as_float(((unsigned int)h) << 16);
}
static __device__ __forceinline__ float bflo(unsigned int p) {
    return __uint_as_float(p << 16);
}
static __device__ __forceinline__ float bfhi(unsigned int p) {
    return __uint_as_float(p & 0xFFFF0000u);
}

// ---------------------------------------------------------------------------
// row_ptr from sorted COO rows: rp[q] = first e with row[e] >= q
// ---------------------------------------------------------------------------
static __global__ void build_rowptr_kernel(const int* __restrict__ row, int E, int N,
                                           int* __restrict__ rp) {
    int e = blockIdx.x * blockDim.x + threadIdx.x;
    if (e >= E) return;
    int r = row[e];
    int prev = (e == 0) ? -1 : row[e - 1];
    for (int q = prev + 1; q <= r; ++q) rp[q] = e;
    if (e == E - 1) {
        for (int q = r + 1; q <= N; ++q) rp[q] = E;
    }
}

// x0 f32 -> bf16
static __global__ void conv_x_kernel(const float4* __restrict__ x, uint2* __restrict__ o) {
    int i = blockIdx.x * blockDim.x + threadIdx.x;   // exactly N*HID/4 threads
    float4 v = x[i];
    uint2 p;
    p.x = (unsigned)f2bf(v.x) | ((unsigned)f2bf(v.y) << 16);
    p.y = (unsigned)f2bf(v.z) | ((unsigned)f2bf(v.w) << 16);
    o[i] = p;
}

// W (L,128,128 [k][n]) -> Wt[mat][n][k] bf16; mats 0-2=Wl, 3-5=Wr
static __global__ void conv_wt_kernel(const float* __restrict__ Wl, const float* __restrict__ Wr,
                                      unsigned short* __restrict__ Wt) {
    int t = blockIdx.x * blockDim.x + threadIdx.x;   // exactly 6*16384 threads
    int mat = t >> 14, idx = t & 16383;
    int n = idx >> 7, k = idx & 127;
    const float* src = (mat < 3) ? (Wl + mat * 16384) : (Wr + (mat - 3) * 16384);
    Wt[t] = f2bf(src[k * HID + n]);
}

// Wout (128x40 [k][c]) -> WoT[c][k] bf16, c padded to 48 with zeros
static __global__ void conv_wout_kernel(const float* __restrict__ Wout,
                                        unsigned short* __restrict__ WoT) {
    int t = blockIdx.x * blockDim.x + threadIdx.x;   // exactly 48*128 threads
    int c = t >> 7, k = t & 127;
    WoT[t] = (c < NCLS) ? f2bf(Wout[k * NCLS + c]) : (unsigned short)0;
}

// bcol2[e] = id[bcol[e]]
static __global__ void gather_col_kernel(const int* __restrict__ bcol, const int* __restrict__ id,
                                         int* __restrict__ bcol2) {
    int e = blockIdx.x * blockDim.x + threadIdx.x;
    if (e < NEDGES) bcol2[e] = id[bcol[e]];
}

// xm = r*x0 + (1-r)*x0[id], stored bf16
static __global__ void mix_init_kernel(const float4* __restrict__ x, const int* __restrict__ id,
                                       const float* __restrict__ mixr, uint2* __restrict__ o) {
    int i = blockIdx.x * blockDim.x + threadIdx.x;   // N*HID/4 threads
    int n = i >> 5, q = i & 31;
    float r = mixr[0];
    float4 a = x[i];
    float4 b = x[(size_t)id[n] * 32 + q];
    uint2 p;
    p.x = (unsigned)f2bf(r * a.x + (1.f - r) * b.x) |
          ((unsigned)f2bf(r * a.y + (1.f - r) * b.y) << 16);
    p.y = (unsigned)f2bf(r * a.z + (1.f - r) * b.z) |
          ((unsigned)f2bf(r * a.w + (1.f - r) * b.w) << 16);
    o[i] = p;
}

// ---------------------------------------------------------------------------
// SpMM: S[n,:] = sum_e val[e] * y[col[e],:]  (y bf16 in, S bf16 out).
// Wave per node, split into 2 half-waves each owning alternate edges; lane
// holds 4 features (8B uint2 loads -> 256B/row gather). Hand-unrolled x2 ->
// 4 edge-gathers in flight per wave. Halves combined via shfl_xor(32).
// ---------------------------------------------------------------------------
static __global__ __launch_bounds__(256) void spmm_kernel(
    const unsigned short* __restrict__ y, const int* __restrict__ col,
    const float* __restrict__ val, const int* __restrict__ rp,
    unsigned short* __restrict__ S) {
    int w = (blockIdx.x * blockDim.x + threadIdx.x) >> 6;   // node
    int l = threadIdx.x & 63;
    int h = l >> 5, j = l & 31;
    int e0 = rp[w], e1 = rp[w + 1];
    float a0 = 0.f, a1 = 0.f, a2 = 0.f, a3 = 0.f;
    int e = e0 + h;
    for (; e + 2 < e1; e += 4) {
        int c0 = col[e], c1 = col[e + 2];
        float v0 = val[e], v1 = val[e + 2];
        uint2 p0 = *(const uint2*)(y + (size_t)c0 * HID + j * 4);
        uint2 p1 = *(const uint2*)(y + (size_t)c1 * HID + j * 4);
        a0 = fmaf(v0, bflo(p0.x), a0); a1 = fmaf(v0, bfhi(p0.x), a1);
        a2 = fmaf(v0, bflo(p0.y), a2); a3 = fmaf(v0, bfhi(p0.y), a3);
        a0 = fmaf(v1, bflo(p1.x), a0); a1 = fmaf(v1, bfhi(p1.x), a1);
        a2 = fmaf(v1, bflo(p1.y), a2); a3 = fmaf(v1, bfhi(p1.y), a3);
    }
    if (e < e1) {
        int c0 = col[e];
        float v0 = val[e];
        uint2 p0 = *(const uint2*)(y + (size_t)c0 * HID + j * 4);
        a0 = fmaf(v0, bflo(p0.x), a0); a1 = fmaf(v0, bfhi(p0.x), a1);
        a2 = fmaf(v0, bflo(p0.y), a2); a3 = fmaf(v0, bfhi(p0.y), a3);
    }
    a0 += __shfl_xor(a0, 32); a1 += __shfl_xor(a1, 32);
    a2 += __shfl_xor(a2, 32); a3 += __shfl_xor(a3, 32);
    if (h == 0) {
        uint2 o;
        o.x = (unsigned)f2bf(a0) | ((unsigned)f2bf(a1) << 16);
        o.y = (unsigned)f2bf(a2) | ((unsigned)f2bf(a3) << 16);
        *(uint2*)(S + (size_t)w * HID + j * 4) = o;
    }
}

// ---------------------------------------------------------------------------
// MFMA GEMM core: C(64x128/block) = A(bf16 Nx128) @ Wt^T (Wt [n][k] bf16).
// 4 waves, wave = 16 rows x 128 cols = 8 col-tiles x 4 K-steps. No LDS.
// A frag: row=lane&15, k=(lane>>4)*8+j. C: col=lane&15, row=(lane>>4)*4+r.
// ---------------------------------------------------------------------------
#define MFMA_CORE(Abuf, Wt)                                                         \
    const int tid = threadIdx.x;                                                    \
    const int lr = tid & 15;                                                        \
    const int lg = (tid >> 4) & 3;                                                  \
    const int r0 = blockIdx.x * 64 + (tid >> 6) * 16;                               \
    float4v acc[8];                                                                 \
    {                                                                               \
        const int arow = min(r0 + lr, NNODES - 1);                                  \
        const unsigned short* ap = (Abuf) + (size_t)arow * HID + lg * 8;            \
        short8v a0 = *(const short8v*)(ap);                                         \
        short8v a1 = *(const short8v*)(ap + 32);                                    \
        short8v a2 = *(const short8v*)(ap + 64);                                    \
        short8v a3 = *(const short8v*)(ap + 96);                                    \
        _Pragma("unroll")                                                           \
        for (int c = 0; c < 8; ++c) {                                               \
            const unsigned short* wp = (Wt) + (size_t)(c * 16 + lr) * HID + lg * 8; \
            short8v b0 = *(const short8v*)(wp);                                     \
            short8v b1 = *(const short8v*)(wp + 32);                                \
            short8v b2 = *(const short8v*)(wp + 64);                                \
            short8v b3 = *(const short8v*)(wp + 96);                                \
            float4v t = {0.f, 0.f, 0.f, 0.f};                                       \
            t = __builtin_amdgcn_mfma_f32_16x16x32_bf16(a0, b0, t, 0, 0, 0);        \
            t = __builtin_amdgcn_mfma_f32_16x16x32_bf16(a1, b1, t, 0, 0, 0);        \
            t = __builtin_amdgcn_mfma_f32_16x16x32_bf16(a2, b2, t, 0, 0, 0);        \
            t = __builtin_amdgcn_mfma_f32_16x16x32_bf16(a3, b3, t, 0, 0, 0);        \
            acc[c] = t;                                                             \
        }                                                                           \
    }

// y = A @ Wl  (bf16 out, no bias)
static __global__ __launch_bounds__(256) void gemm_y_kernel(
    const unsigned short* __restrict__ A, const unsigned short* __restrict__ Wt,
    unsigned short* __restrict__ out) {
    MFMA_CORE(A, Wt)
#pragma unroll
    for (int c = 0; c < 8; ++c) {
#pragma unroll
        for (int r = 0; r < 4; ++r) {
            int m = r0 + lg * 4 + r;
            if (m < NNODES) out[(size_t)m * HID + c * 16 + lr] = f2bf(acc[c][r]);
        }
    }
}

// h = relu(S + A @ Wr + b)  (S bf16, bf16 out)
static __global__ __launch_bounds__(256) void gemm_h_kernel(
    const unsigned short* __restrict__ A, const unsigned short* __restrict__ Wt,
    const unsigned short* __restrict__ S, const float* __restrict__ bias,
    unsigned short* __restrict__ out) {
    MFMA_CORE(A, Wt)
#pragma unroll
    for (int c = 0; c < 8; ++c) {
        float bv = bias[c * 16 + lr];
#pragma unroll
        for (int r = 0; r < 4; ++r) {
            int m = r0 + lg * 4 + r;
            if (m < NNODES) {
                size_t idx = (size_t)m * HID + c * 16 + lr;
                out[idx] = f2bf(fmaxf(acc[c][r] + bf2f(S[idx]) + bv, 0.f));
            }
        }
    }
}

// z = A @ Wr + b; xm = r*relu(S+z) + (1-r)*relu(T+z)  (S,T bf16; in-place xm)
static __global__ __launch_bounds__(256) void gemm_mix_kernel(
    const unsigned short* A, const unsigned short* __restrict__ Wt,
    const unsigned short* __restrict__ S, const unsigned short* __restrict__ T,
    const float* __restrict__ bias, const float* __restrict__ mixr,
    unsigned short* out) {
    MFMA_CORE(A, Wt)
    const float rr = mixr[0];
#pragma unroll
    for (int c = 0; c < 8; ++c) {
        float bv = bias[c * 16 + lr];
#pragma unroll
        for (int r = 0; r < 4; ++r) {
            int m = r0 + lg * 4 + r;
            if (m < NNODES) {
                size_t idx = (size_t)m * HID + c * 16 + lr;
                float z = acc[c][r] + bv;
                float xa = fmaxf(bf2f(S[idx]) + z, 0.f);
                float xb = fmaxf(bf2f(T[idx]) + z, 0.f);
                out[idx] = f2bf(rr * xa + (1.f - rr) * xb);
            }
        }
    }
}

// ---------------------------------------------------------------------------
// Head: logits = xm @ WoT^T + bout (48-col padded MFMA), then log_softmax via
// shfl_xor reduction over the 16-lane class groups. Wave = 16 rows.
// ---------------------------------------------------------------------------
static __global__ __launch_bounds__(256) void head_kernel(
    const unsigned short* __restrict__ xm, const unsigned short* __restrict__ WoT,
    const float* __restrict__ bout, float* __restrict__ out) {
    const int tid = threadIdx.x;
    const int lr = tid & 15;
    const int lg = (tid >> 4) & 3;
    const int r0 = blockIdx.x * 64 + (tid >> 6) * 16;
    const int arow = min(r0 + lr, NNODES - 1);
    const unsigned short* ap = xm + (size_t)arow * HID + lg * 8;
    short8v a0 = *(const short8v*)(ap);
    short8v a1 = *(const short8v*)(ap + 32);
    short8v a2 = *(const short8v*)(ap + 64);
    short8v a3 = *(const short8v*)(ap + 96);
    float4v acc[3];
#pragma unroll
    for (int c = 0; c < 3; ++c) {
        const unsigned short* wp = WoT + (size_t)(c * 16 + lr) * HID + lg * 8;
        short8v b0 = *(const short8v*)(wp);
        short8v b1 = *(const short8v*)(wp + 32);
        short8v b2 = *(const short8v*)(wp + 64);
        short8v b3 = *(const short8v*)(wp + 96);
        float4v t = {0.f, 0.f, 0.f, 0.f};
        t = __builtin_amdgcn_mfma_f32_16x16x32_bf16(a0, b0, t, 0, 0, 0);
        t = __builtin_amdgcn_mfma_f32_16x16x32_bf16(a1, b1, t, 0, 0, 0);
        t = __builtin_amdgcn_mfma_f32_16x16x32_bf16(a2, b2, t, 0, 0, 0);
        t = __builtin_amdgcn_mfma_f32_16x16x32_bf16(a3, b3, t, 0, 0, 0);
        acc[c] = t;
    }
    float bia0 = bout[lr];
    float bia1 = bout[16 + lr];
    float bia2 = (lr < 8) ? bout[32 + lr] : 0.f;
#pragma unroll
    for (int r = 0; r < 4; ++r) {
        float l0 = acc[0][r] + bia0;
        float l1 = acc[1][r] + bia1;
        float l2 = (lr < 8) ? (acc[2][r] + bia2) : -INFINITY;
        float mx = fmaxf(fmaxf(l0, l1), l2);
#pragma unroll
        for (int off = 1; off < 16; off <<= 1) mx = fmaxf(mx, __shfl_xor(mx, off));
        float s = expf(l0 - mx) + expf(l1 - mx) + ((lr < 8) ? expf(l2 - mx) : 0.f);
#pragma unroll
        for (int off = 1; off < 16; off <<= 1) s += __shfl_xor(s, off);
        float lse = mx + logf(s);
        int m = r0 + lg * 4 + r;
        if (m < NNODES) {
            out[(size_t)m * NCLS + lr] = l0 - lse;
            out[(size_t)m * NCLS + 16 + lr] = l1 - lse;
            if (lr < 8) out[(size_t)m * NCLS + 32 + lr] = l2 - lse;
        }
    }
}

// ---------------------------------------------------------------------------
extern "C" void kernel_launch(void* const* d_in, const int* in_sizes, int n_in,
                              void* d_out, int out_size, void* d_ws, size_t ws_size,
                              hipStream_t stream) {
    const float* x0   = (const float*)d_in[0];
    const int*   arow = (const int*)d_in[1];
    const int*   acol = (const int*)d_in[2];
    const float* aval = (const float*)d_in[3];
    const int*   brow = (const int*)d_in[4];
    const int*   bcol = (const int*)d_in[5];
    const float* bval = (const float*)d_in[6];
    const float* mixr = (const float*)d_in[7];
    const int*   id   = (const int*)d_in[8];
    const float* Wl   = (const float*)d_in[9];
    const float* Wr   = (const float*)d_in[10];
    const float* bs   = (const float*)d_in[11];
    const float* Wout = (const float*)d_in[12];
    const float* bout = (const float*)d_in[13];
    float* out = (float*)d_out;

    const size_t NF = (size_t)NNODES * HID;   // 6.4M
    unsigned short* x0b = (unsigned short*)d_ws;
    unsigned short* xmb = x0b + NF;
    unsigned short* h1b = xmb + NF;
    unsigned short* h2b = h1b + NF;
    unsigned short* yb  = h2b + NF;
    unsigned short* S   = yb + NF;
    unsigned short* T   = S + NF;
    unsigned short* Wt  = T + NF;             // 6 * 16384 bf16
    unsigned short* WoT = Wt + 6 * 16384;     // 48 * 128 bf16
    int* rpa = (int*)(WoT + 48 * 128);
    int* rpb = rpa + (NNODES + 1);
    int* bcol2 = rpb + (NNODES + 1);

    const int gE = (NEDGES + 255) / 256;      // 1954
    const int gC = NNODES * HID / 4 / 256;    // 6250
    const int gG = (NNODES + 63) / 64;        // 782
    const int gS = NNODES * 64 / 256;         // 12500

    build_rowptr_kernel<<<gE, 256, 0, stream>>>(arow, NEDGES, NNODES, rpa);
    build_rowptr_kernel<<<gE, 256, 0, stream>>>(brow, NEDGES, NNODES, rpb);
    conv_x_kernel<<<gC, 256, 0, stream>>>((const float4*)x0, (uint2*)x0b);
    conv_wt_kernel<<<6 * 16384 / 256, 256, 0, stream>>>(Wl, Wr, Wt);
    conv_wout_kernel<<<48 * 128 / 256, 256, 0, stream>>>(Wout, WoT);
    gather_col_kernel<<<gE, 256, 0, stream>>>(bcol, id, bcol2);
    mix_init_kernel<<<gC, 256, 0, stream>>>((const float4*)x0, id, mixr, (uint2*)xmb);

    // ---- layer 0 (aggr_xs[0] = x0)
    gemm_y_kernel<<<gG, 256, 0, stream>>>(x0b, Wt + 0 * 16384, yb);
    spmm_kernel<<<gS, 256, 0, stream>>>(yb, acol, aval, rpa, S);
    spmm_kernel<<<gS, 256, 0, stream>>>(yb, bcol2, bval, rpb, T);
    gemm_h_kernel<<<gG, 256, 0, stream>>>(x0b, Wt + 3 * 16384, S, bs, h1b);
    gemm_mix_kernel<<<gG, 256, 0, stream>>>(xmb, Wt + 3 * 16384, S, T, bs, mixr, xmb);

    // ---- layer 1 (aggr_xs[1] = h1)
    gemm_y_kernel<<<gG, 256, 0, stream>>>(h1b, Wt + 1 * 16384, yb);
    spmm_kernel<<<gS, 256, 0, stream>>>(yb, acol, aval, rpa, S);
    spmm_kernel<<<gS, 256, 0, stream>>>(yb, bcol2, bval, rpb, T);
    gemm_h_kernel<<<gG, 256, 0, stream>>>(h1b, Wt + 4 * 16384, S, bs + 128, h2b);
    gemm_mix_kernel<<<gG, 256, 0, stream>>>(xmb, Wt + 4 * 16384, S, T, bs + 128, mixr, xmb);

    // ---- layer 2 (aggr_xs[2] = h2)
    gemm_y_kernel<<<gG, 256, 0, stream>>>(h2b, Wt + 2 * 16384, yb);
    spmm_kernel<<<gS, 256, 0, stream>>>(yb, acol, aval, rpa, S);
    spmm_kernel<<<gS, 256, 0, stream>>>(yb, bcol2, bval, rpb, T);
    gemm_mix_kernel<<<gG, 256, 0, stream>>>(xmb, Wt + 5 * 16384, S, T, bs + 256, mixr, xmb);

    head_kernel<<<gG, 256, 0, stream>>>(xmb, WoT, bout, out);
}

// Round 4
// 319.032 us; speedup vs baseline: 3.1090x; 1.2471x over previous
//
#include <hip/hip_runtime.h>
#include <math.h>

#define NNODES 50000
#define NEDGES 500000
#define HID 128
#define NCLS 40

using short8v = __attribute__((ext_vector_type(8))) short;
using float4v = __attribute__((ext_vector_type(4))) float;

static __device__ __forceinline__ unsigned short f2bf(float f) {
    unsigned int u = __float_as_uint(f);
    u += 0x7FFFu + ((u >> 16) & 1u);   // RNE
    return (unsigned short)(u >> 16);
}
static __device__ __forceinline__ float bf2f(unsigned short h) {
    return __uint_as_float(((unsigned int)h) << 16);
}
static __device__ __forceinline__ float bflo(unsigned int p) {
    return __uint_as_float(p << 16);
}
static __device__ __forceinline__ float bfhi(unsigned int p) {
    return __uint_as_float(p & 0xFFFF0000u);
}

// ---------------------------------------------------------------------------
// prep_edges: [0,gE) rowptr A; [gE,2gE) rowptr B; [2gE,3gE) bcol2 = id[bcol]
// ---------------------------------------------------------------------------
static __device__ __forceinline__ void rowptr_body(const int* __restrict__ row,
                                                   int e, int* __restrict__ rp) {
    if (e >= NEDGES) return;
    int r = row[e];
    int prev = (e == 0) ? -1 : row[e - 1];
    for (int q = prev + 1; q <= r; ++q) rp[q] = e;
    if (e == NEDGES - 1) {
        for (int q = r + 1; q <= NNODES; ++q) rp[q] = NEDGES;
    }
}

static __global__ void prep_edges_kernel(const int* __restrict__ arow,
                                         const int* __restrict__ brow,
                                         const int* __restrict__ bcol,
                                         const int* __restrict__ id,
                                         int* __restrict__ rpa, int* __restrict__ rpb,
                                         int* __restrict__ bcol2, int gE) {
    int bid = blockIdx.x;
    if (bid < gE) {
        rowptr_body(arow, bid * 256 + threadIdx.x, rpa);
    } else if (bid < 2 * gE) {
        rowptr_body(brow, (bid - gE) * 256 + threadIdx.x, rpb);
    } else {
        int e = (bid - 2 * gE) * 256 + threadIdx.x;
        if (e < NEDGES) bcol2[e] = id[bcol[e]];
    }
}

// ---------------------------------------------------------------------------
// prep_x: x0b = bf16(x0); xmb = bf16(r*x0 + (1-r)*x0[id])
// ---------------------------------------------------------------------------
static __global__ void prep_x_kernel(const float4* __restrict__ x, const int* __restrict__ id,
                                     const float* __restrict__ mixr,
                                     uint2* __restrict__ x0b, uint2* xmb) {
    int i = blockIdx.x * blockDim.x + threadIdx.x;   // exactly N*HID/4
    int n = i >> 5, qq = i & 31;
    float r = mixr[0];
    float4 a = x[i];
    float4 b = x[(size_t)id[n] * 32 + qq];
    uint2 pa, pm;
    pa.x = (unsigned)f2bf(a.x) | ((unsigned)f2bf(a.y) << 16);
    pa.y = (unsigned)f2bf(a.z) | ((unsigned)f2bf(a.w) << 16);
    pm.x = (unsigned)f2bf(r * a.x + (1.f - r) * b.x) |
           ((unsigned)f2bf(r * a.y + (1.f - r) * b.y) << 16);
    pm.y = (unsigned)f2bf(r * a.z + (1.f - r) * b.z) |
           ((unsigned)f2bf(r * a.w + (1.f - r) * b.w) << 16);
    x0b[i] = pa;
    xmb[i] = pm;
}

// ---------------------------------------------------------------------------
// prep_w: Wt[mat][n][k] for 6 mats (0-2 Wl, 3-5 Wr), then WoT[c][k] (48-pad)
// ---------------------------------------------------------------------------
static __global__ void prep_w_kernel(const float* __restrict__ Wl, const float* __restrict__ Wr,
                                     const float* __restrict__ Wout,
                                     unsigned short* __restrict__ Wt,
                                     unsigned short* __restrict__ WoT) {
    int t = blockIdx.x * blockDim.x + threadIdx.x;   // exactly 6*16384 + 48*128
    if (t < 6 * 16384) {
        int mat = t >> 14, idx = t & 16383;
        int n = idx >> 7, k = idx & 127;
        const float* src = (mat < 3) ? (Wl + mat * 16384) : (Wr + (mat - 3) * 16384);
        Wt[t] = f2bf(src[k * HID + n]);
    } else {
        int u = t - 6 * 16384;
        int c = u >> 7, k = u & 127;
        WoT[u] = (c < NCLS) ? f2bf(Wout[k * NCLS + c]) : (unsigned short)0;
    }
}

// ---------------------------------------------------------------------------
// spmm2: wave w<N -> S[w,:] = sum val[e]*y[colA[e],:]; w>=N -> T via B edges.
// Quarter-wave (16 lanes x 16B) per row gather, unroll x2 -> 8 rows in flight.
// ---------------------------------------------------------------------------
static __global__ __launch_bounds__(256) void spmm2_kernel(
    const unsigned short* __restrict__ y,
    const int* __restrict__ colA, const float* __restrict__ valA,
    const int* __restrict__ rpA, unsigned short* __restrict__ SA,
    const int* __restrict__ colB, const float* __restrict__ valB,
    const int* __restrict__ rpB, unsigned short* __restrict__ SB) {
    int w = blockIdx.x * 4 + (threadIdx.x >> 6);
    const int l = threadIdx.x & 63;
    const int q = l >> 4, j = l & 15;
    const int* col; const float* val; const int* rp; unsigned short* dst; int node;
    if (w < NNODES) { col = colA; val = valA; rp = rpA; dst = SA; node = w; }
    else            { col = colB; val = valB; rp = rpB; dst = SB; node = w - NNODES; }
    int e0 = rp[node], e1 = rp[node + 1];
    float a0 = 0.f, a1 = 0.f, a2 = 0.f, a3 = 0.f, a4 = 0.f, a5 = 0.f, a6 = 0.f, a7 = 0.f;
    int e = e0 + q;
    for (; e + 4 < e1; e += 8) {
        int c0 = col[e], c1 = col[e + 4];
        float v0 = val[e], v1 = val[e + 4];
        uint4 p0 = *(const uint4*)(y + (size_t)c0 * HID + j * 8);
        uint4 p1 = *(const uint4*)(y + (size_t)c1 * HID + j * 8);
        a0 = fmaf(v0, bflo(p0.x), a0); a1 = fmaf(v0, bfhi(p0.x), a1);
        a2 = fmaf(v0, bflo(p0.y), a2); a3 = fmaf(v0, bfhi(p0.y), a3);
        a4 = fmaf(v0, bflo(p0.z), a4); a5 = fmaf(v0, bfhi(p0.z), a5);
        a6 = fmaf(v0, bflo(p0.w), a6); a7 = fmaf(v0, bfhi(p0.w), a7);
        a0 = fmaf(v1, bflo(p1.x), a0); a1 = fmaf(v1, bfhi(p1.x), a1);
        a2 = fmaf(v1, bflo(p1.y), a2); a3 = fmaf(v1, bfhi(p1.y), a3);
        a4 = fmaf(v1, bflo(p1.z), a4); a5 = fmaf(v1, bfhi(p1.z), a5);
        a6 = fmaf(v1, bflo(p1.w), a6); a7 = fmaf(v1, bfhi(p1.w), a7);
    }
    if (e < e1) {
        int c0 = col[e];
        float v0 = val[e];
        uint4 p0 = *(const uint4*)(y + (size_t)c0 * HID + j * 8);
        a0 = fmaf(v0, bflo(p0.x), a0); a1 = fmaf(v0, bfhi(p0.x), a1);
        a2 = fmaf(v0, bflo(p0.y), a2); a3 = fmaf(v0, bfhi(p0.y), a3);
        a4 = fmaf(v0, bflo(p0.z), a4); a5 = fmaf(v0, bfhi(p0.z), a5);
        a6 = fmaf(v0, bflo(p0.w), a6); a7 = fmaf(v0, bfhi(p0.w), a7);
    }
    a0 += __shfl_xor(a0, 16); a1 += __shfl_xor(a1, 16);
    a2 += __shfl_xor(a2, 16); a3 += __shfl_xor(a3, 16);
    a4 += __shfl_xor(a4, 16); a5 += __shfl_xor(a5, 16);
    a6 += __shfl_xor(a6, 16); a7 += __shfl_xor(a7, 16);
    a0 += __shfl_xor(a0, 32); a1 += __shfl_xor(a1, 32);
    a2 += __shfl_xor(a2, 32); a3 += __shfl_xor(a3, 32);
    a4 += __shfl_xor(a4, 32); a5 += __shfl_xor(a5, 32);
    a6 += __shfl_xor(a6, 32); a7 += __shfl_xor(a7, 32);
    if (l < 16) {
        uint4 o;
        o.x = (unsigned)f2bf(a0) | ((unsigned)f2bf(a1) << 16);
        o.y = (unsigned)f2bf(a2) | ((unsigned)f2bf(a3) << 16);
        o.z = (unsigned)f2bf(a4) | ((unsigned)f2bf(a5) << 16);
        o.w = (unsigned)f2bf(a6) | ((unsigned)f2bf(a7) << 16);
        *(uint4*)(dst + (size_t)node * HID + l * 8) = o;
    }
}

// ---------------------------------------------------------------------------
// gemm_y: y = A @ Wt^T (bf16 out). Standalone (used once for y0 = x0 @ Wl0).
// A frag: row=lane&15, k=(lane>>4)*8+j. C: col=lane&15, row=(lane>>4)*4+reg.
// ---------------------------------------------------------------------------
static __global__ __launch_bounds__(256) void gemm_y_kernel(
    const unsigned short* __restrict__ A, const unsigned short* __restrict__ Wt,
    unsigned short* __restrict__ out) {
    const int tid = threadIdx.x;
    const int lr = tid & 15;
    const int lg = (tid >> 4) & 3;
    const int r0 = blockIdx.x * 64 + (tid >> 6) * 16;
    const int arow = min(r0 + lr, NNODES - 1);
    const unsigned short* ap = A + (size_t)arow * HID + lg * 8;
    short8v a0 = *(const short8v*)(ap);
    short8v a1 = *(const short8v*)(ap + 32);
    short8v a2 = *(const short8v*)(ap + 64);
    short8v a3 = *(const short8v*)(ap + 96);
    float4v acc[8];
#pragma unroll
    for (int c = 0; c < 8; ++c) {
        const unsigned short* wp = Wt + (size_t)(c * 16 + lr) * HID + lg * 8;
        short8v b0 = *(const short8v*)(wp);
        short8v b1 = *(const short8v*)(wp + 32);
        short8v b2 = *(const short8v*)(wp + 64);
        short8v b3 = *(const short8v*)(wp + 96);
        float4v t = {0.f, 0.f, 0.f, 0.f};
        t = __builtin_amdgcn_mfma_f32_16x16x32_bf16(a0, b0, t, 0, 0, 0);
        t = __builtin_amdgcn_mfma_f32_16x16x32_bf16(a1, b1, t, 0, 0, 0);
        t = __builtin_amdgcn_mfma_f32_16x16x32_bf16(a2, b2, t, 0, 0, 0);
        t = __builtin_amdgcn_mfma_f32_16x16x32_bf16(a3, b3, t, 0, 0, 0);
        acc[c] = t;
    }
#pragma unroll
    for (int c = 0; c < 8; ++c) {
#pragma unroll
        for (int r = 0; r < 4; ++r) {
            int m = r0 + lg * 4 + r;
            if (m < NNODES) out[(size_t)m * HID + c * 16 + lr] = f2bf(acc[c][r]);
        }
    }
}

// ---------------------------------------------------------------------------
// fused_layer<DO_HY>:
//   z = xm @ Wr + b (mix core); h core (DO_HY): hv = relu(S + Ah@Wr + b)
//   xm' = r*relu(S+z) + (1-r)*relu(T+z)
//   DO_HY:  write h, xm'; y' = h @ WtLn via LDS transpose -> write y
//   !DO_HY: xm' -> LDS; head: logits = xm' @ WoT + bout; log_softmax -> out
// ---------------------------------------------------------------------------
template <bool DO_HY>
static __global__ __launch_bounds__(256) void fused_layer_kernel(
    const unsigned short* __restrict__ Ah,
    const unsigned short* xmIn,
    const unsigned short* __restrict__ WtR,
    const unsigned short* __restrict__ WtLn,
    const unsigned short* __restrict__ S,
    const unsigned short* __restrict__ T,
    const float* __restrict__ bias,
    const float* __restrict__ mixr,
    unsigned short* __restrict__ hOut,
    unsigned short* __restrict__ yOut,
    unsigned short* xmOut,
    const unsigned short* __restrict__ WoT,
    const float* __restrict__ bout,
    float* __restrict__ out) {
    __shared__ __align__(16) unsigned short hs[64][136];   // +8 pad: bank spread
    const int tid = threadIdx.x;
    const int lr = tid & 15;
    const int lg = (tid >> 4) & 3;
    const int wv = tid >> 6;
    const int r0 = blockIdx.x * 64 + wv * 16;
    const float rr = mixr[0];

    const int arow = min(r0 + lr, NNODES - 1);
    const unsigned short* xp = xmIn + (size_t)arow * HID + lg * 8;
    short8v ax0 = *(const short8v*)(xp);
    short8v ax1 = *(const short8v*)(xp + 32);
    short8v ax2 = *(const short8v*)(xp + 64);
    short8v ax3 = *(const short8v*)(xp + 96);
    short8v ah0, ah1, ah2, ah3;
    if constexpr (DO_HY) {
        const unsigned short* hp = Ah + (size_t)arow * HID + lg * 8;
        ah0 = *(const short8v*)(hp);
        ah1 = *(const short8v*)(hp + 32);
        ah2 = *(const short8v*)(hp + 64);
        ah3 = *(const short8v*)(hp + 96);
    }

    float4v accz[8], acch[8];
#pragma unroll
    for (int c = 0; c < 8; ++c) {
        const unsigned short* wp = WtR + (size_t)(c * 16 + lr) * HID + lg * 8;
        short8v b0 = *(const short8v*)(wp);
        short8v b1 = *(const short8v*)(wp + 32);
        short8v b2 = *(const short8v*)(wp + 64);
        short8v b3 = *(const short8v*)(wp + 96);
        float4v t = {0.f, 0.f, 0.f, 0.f};
        t = __builtin_amdgcn_mfma_f32_16x16x32_bf16(ax0, b0, t, 0, 0, 0);
        t = __builtin_amdgcn_mfma_f32_16x16x32_bf16(ax1, b1, t, 0, 0, 0);
        t = __builtin_amdgcn_mfma_f32_16x16x32_bf16(ax2, b2, t, 0, 0, 0);
        t = __builtin_amdgcn_mfma_f32_16x16x32_bf16(ax3, b3, t, 0, 0, 0);
        accz[c] = t;
        if constexpr (DO_HY) {
            float4v u = {0.f, 0.f, 0.f, 0.f};
            u = __builtin_amdgcn_mfma_f32_16x16x32_bf16(ah0, b0, u, 0, 0, 0);
            u = __builtin_amdgcn_mfma_f32_16x16x32_bf16(ah1, b1, u, 0, 0, 0);
            u = __builtin_amdgcn_mfma_f32_16x16x32_bf16(ah2, b2, u, 0, 0, 0);
            u = __builtin_amdgcn_mfma_f32_16x16x32_bf16(ah3, b3, u, 0, 0, 0);
            acch[c] = u;
        }
    }

    // epilogue: mix (+h)
#pragma unroll
    for (int c = 0; c < 8; ++c) {
        const int colc = c * 16 + lr;
        const float bv = bias[colc];
#pragma unroll
        for (int r = 0; r < 4; ++r) {
            const int m = r0 + lg * 4 + r;
            const int mc = min(m, NNODES - 1);
            const size_t idx = (size_t)mc * HID + colc;
            const int lrow = wv * 16 + lg * 4 + r;
            const float sv = bf2f(S[idx]);
            const float z = accz[c][r] + bv;
            const float xa = fmaxf(sv + z, 0.f);
            const float xb = fmaxf(bf2f(T[idx]) + z, 0.f);
            const unsigned short xmv = f2bf(rr * xa + (1.f - rr) * xb);
            if constexpr (DO_HY) {
                const unsigned short hv = f2bf(fmaxf(acch[c][r] + sv + bv, 0.f));
                hs[lrow][colc] = hv;
                if (m < NNODES) {
                    hOut[idx] = hv;
                    xmOut[idx] = xmv;
                }
            } else {
                hs[lrow][colc] = xmv;
            }
        }
    }
    __syncthreads();

    // stage 2: A-frags from LDS tile (row = wv*16 + lr, k = lg*8 + 32q)
    const unsigned short* lp = &hs[wv * 16 + lr][lg * 8];
    short8v c0 = *(const short8v*)(lp);
    short8v c1 = *(const short8v*)(lp + 32);
    short8v c2 = *(const short8v*)(lp + 64);
    short8v c3 = *(const short8v*)(lp + 96);

    if constexpr (DO_HY) {
        float4v accy[8];
#pragma unroll
        for (int c = 0; c < 8; ++c) {
            const unsigned short* wp = WtLn + (size_t)(c * 16 + lr) * HID + lg * 8;
            short8v b0 = *(const short8v*)(wp);
            short8v b1 = *(const short8v*)(wp + 32);
            short8v b2 = *(const short8v*)(wp + 64);
            short8v b3 = *(const short8v*)(wp + 96);
            float4v t = {0.f, 0.f, 0.f, 0.f};
            t = __builtin_amdgcn_mfma_f32_16x16x32_bf16(c0, b0, t, 0, 0, 0);
            t = __builtin_amdgcn_mfma_f32_16x16x32_bf16(c1, b1, t, 0, 0, 0);
            t = __builtin_amdgcn_mfma_f32_16x16x32_bf16(c2, b2, t, 0, 0, 0);
            t = __builtin_amdgcn_mfma_f32_16x16x32_bf16(c3, b3, t, 0, 0, 0);
            accy[c] = t;
        }
#pragma unroll
        for (int c = 0; c < 8; ++c) {
#pragma unroll
            for (int r = 0; r < 4; ++r) {
                int m = r0 + lg * 4 + r;
                if (m < NNODES) yOut[(size_t)m * HID + c * 16 + lr] = f2bf(accy[c][r]);
            }
        }
    } else {
        float4v acc[3];
#pragma unroll
        for (int c = 0; c < 3; ++c) {
            const unsigned short* wp = WoT + (size_t)(c * 16 + lr) * HID + lg * 8;
            short8v b0 = *(const short8v*)(wp);
            short8v b1 = *(const short8v*)(wp + 32);
            short8v b2 = *(const short8v*)(wp + 64);
            short8v b3 = *(const short8v*)(wp + 96);
            float4v t = {0.f, 0.f, 0.f, 0.f};
            t = __builtin_amdgcn_mfma_f32_16x16x32_bf16(c0, b0, t, 0, 0, 0);
            t = __builtin_amdgcn_mfma_f32_16x16x32_bf16(c1, b1, t, 0, 0, 0);
            t = __builtin_amdgcn_mfma_f32_16x16x32_bf16(c2, b2, t, 0, 0, 0);
            t = __builtin_amdgcn_mfma_f32_16x16x32_bf16(c3, b3, t, 0, 0, 0);
            acc[c] = t;
        }
        const float bia0 = bout[lr];
        const float bia1 = bout[16 + lr];
        const float bia2 = (lr < 8) ? bout[32 + lr] : 0.f;
#pragma unroll
        for (int r = 0; r < 4; ++r) {
            float l0 = acc[0][r] + bia0;
            float l1 = acc[1][r] + bia1;
            float l2 = (lr < 8) ? (acc[2][r] + bia2) : -INFINITY;
            float mx = fmaxf(fmaxf(l0, l1), l2);
#pragma unroll
            for (int off = 1; off < 16; off <<= 1) mx = fmaxf(mx, __shfl_xor(mx, off));
            float s = expf(l0 - mx) + expf(l1 - mx) + ((lr < 8) ? expf(l2 - mx) : 0.f);
#pragma unroll
            for (int off = 1; off < 16; off <<= 1) s += __shfl_xor(s, off);
            float lse = mx + logf(s);
            int m = r0 + lg * 4 + r;
            if (m < NNODES) {
                out[(size_t)m * NCLS + lr] = l0 - lse;
                out[(size_t)m * NCLS + 16 + lr] = l1 - lse;
                if (lr < 8) out[(size_t)m * NCLS + 32 + lr] = l2 - lse;
            }
        }
    }
}

// ---------------------------------------------------------------------------
extern "C" void kernel_launch(void* const* d_in, const int* in_sizes, int n_in,
                              void* d_out, int out_size, void* d_ws, size_t ws_size,
                              hipStream_t stream) {
    const float* x0   = (const float*)d_in[0];
    const int*   arow = (const int*)d_in[1];
    const int*   acol = (const int*)d_in[2];
    const float* aval = (const float*)d_in[3];
    const int*   brow = (const int*)d_in[4];
    const int*   bcol = (const int*)d_in[5];
    const float* bval = (const float*)d_in[6];
    const float* mixr = (const float*)d_in[7];
    const int*   id   = (const int*)d_in[8];
    const float* Wl   = (const float*)d_in[9];
    const float* Wr   = (const float*)d_in[10];
    const float* bs   = (const float*)d_in[11];
    const float* Wout = (const float*)d_in[12];
    const float* bout = (const float*)d_in[13];
    float* out = (float*)d_out;

    const size_t NF = (size_t)NNODES * HID;   // 6.4M
    unsigned short* x0b = (unsigned short*)d_ws;
    unsigned short* xmb = x0b + NF;
    unsigned short* h1b = xmb + NF;
    unsigned short* h2b = h1b + NF;
    unsigned short* yb  = h2b + NF;
    unsigned short* S   = yb + NF;
    unsigned short* T   = S + NF;
    unsigned short* Wt  = T + NF;             // 6 * 16384 bf16
    unsigned short* WoT = Wt + 6 * 16384;     // 48 * 128 bf16
    int* rpa = (int*)(WoT + 48 * 128);
    int* rpb = rpa + (NNODES + 1);
    int* bcol2 = rpb + (NNODES + 1);

    const int gE = (NEDGES + 255) / 256;      // 1954
    const int gC = NNODES * HID / 4 / 256;    // 6250
    const int gG = (NNODES + 63) / 64;        // 782
    const int gS2 = 2 * NNODES * 64 / 256;    // 25000

    prep_edges_kernel<<<3 * gE, 256, 0, stream>>>(arow, brow, bcol, id, rpa, rpb, bcol2, gE);
    prep_x_kernel<<<gC, 256, 0, stream>>>((const float4*)x0, id, mixr, (uint2*)x0b, (uint2*)xmb);
    prep_w_kernel<<<(6 * 16384 + 48 * 128) / 256, 256, 0, stream>>>(Wl, Wr, Wout, Wt, WoT);

    // y0 = x0 @ Wl0
    gemm_y_kernel<<<gG, 256, 0, stream>>>(x0b, Wt + 0 * 16384, yb);

    // ---- layer 0
    spmm2_kernel<<<gS2, 256, 0, stream>>>(yb, acol, aval, rpa, S, bcol2, bval, rpb, T);
    fused_layer_kernel<true><<<gG, 256, 0, stream>>>(
        x0b, xmb, Wt + 3 * 16384, Wt + 1 * 16384, S, T, bs, mixr,
        h1b, yb, xmb, nullptr, nullptr, nullptr);

    // ---- layer 1
    spmm2_kernel<<<gS2, 256, 0, stream>>>(yb, acol, aval, rpa, S, bcol2, bval, rpb, T);
    fused_layer_kernel<true><<<gG, 256, 0, stream>>>(
        h1b, xmb, Wt + 4 * 16384, Wt + 2 * 16384, S, T, bs + 128, mixr,
        h2b, yb, xmb, nullptr, nullptr, nullptr);

    // ---- layer 2 (+ head)
    spmm2_kernel<<<gS2, 256, 0, stream>>>(yb, acol, aval, rpa, S, bcol2, bval, rpb, T);
    fused_layer_kernel<false><<<gG, 256, 0, stream>>>(
        h2b, xmb, Wt + 5 * 16384, nullptr, S, T, bs + 256, mixr,
        nullptr, nullptr, nullptr, WoT, bout, out);
}

// Round 5
// 290.152 us; speedup vs baseline: 3.4184x; 1.0995x over previous
//
#include <hip/hip_runtime.h>
#include <math.h>

#define NNODES 50000
#define NEDGES 500000
#define HID 128
#define NCLS 40

using short8v = __attribute__((ext_vector_type(8))) short;
using float4v = __attribute__((ext_vector_type(4))) float;

static __device__ __forceinline__ unsigned short f2bf(float f) {
    unsigned int u = __float_as_uint(f);
    u += 0x7FFFu + ((u >> 16) & 1u);   // RNE
    return (unsigned short)(u >> 16);
}
static __device__ __forceinline__ float bf2f(unsigned short h) {
    return __uint_as_float(((unsigned int)h) << 16);
}
static __device__ __forceinline__ float bflo(unsigned int p) {
    return __uint_as_float(p << 16);
}
static __device__ __forceinline__ float bfhi(unsigned int p) {
    return __uint_as_float(p & 0xFFFF0000u);
}

// ---------------------------------------------------------------------------
// prep_edges: [0,gE) rowptr A; [gE,2gE) rowptr B; [2gE,3gE) bcol2 = id[bcol]
// ---------------------------------------------------------------------------
static __device__ __forceinline__ void rowptr_body(const int* __restrict__ row,
                                                   int e, int* __restrict__ rp) {
    if (e >= NEDGES) return;
    int r = row[e];
    int prev = (e == 0) ? -1 : row[e - 1];
    for (int q = prev + 1; q <= r; ++q) rp[q] = e;
    if (e == NEDGES - 1) {
        for (int q = r + 1; q <= NNODES; ++q) rp[q] = NEDGES;
    }
}

static __global__ void prep_edges_kernel(const int* __restrict__ arow,
                                         const int* __restrict__ brow,
                                         const int* __restrict__ bcol,
                                         const int* __restrict__ id,
                                         int* __restrict__ rpa, int* __restrict__ rpb,
                                         int* __restrict__ bcol2, int gE) {
    int bid = blockIdx.x;
    if (bid < gE) {
        rowptr_body(arow, bid * 256 + threadIdx.x, rpa);
    } else if (bid < 2 * gE) {
        rowptr_body(brow, (bid - gE) * 256 + threadIdx.x, rpb);
    } else {
        int e = (bid - 2 * gE) * 256 + threadIdx.x;
        if (e < NEDGES) bcol2[e] = id[bcol[e]];
    }
}

// ---------------------------------------------------------------------------
// prep_x: x0b = bf16(x0); xmb = bf16(r*x0 + (1-r)*x0[id])
// ---------------------------------------------------------------------------
static __global__ void prep_x_kernel(const float4* __restrict__ x, const int* __restrict__ id,
                                     const float* __restrict__ mixr,
                                     uint2* __restrict__ x0b, uint2* xmb) {
    int i = blockIdx.x * blockDim.x + threadIdx.x;   // exactly N*HID/4
    int n = i >> 5, qq = i & 31;
    float r = mixr[0];
    float4 a = x[i];
    float4 b = x[(size_t)id[n] * 32 + qq];
    uint2 pa, pm;
    pa.x = (unsigned)f2bf(a.x) | ((unsigned)f2bf(a.y) << 16);
    pa.y = (unsigned)f2bf(a.z) | ((unsigned)f2bf(a.w) << 16);
    pm.x = (unsigned)f2bf(r * a.x + (1.f - r) * b.x) |
           ((unsigned)f2bf(r * a.y + (1.f - r) * b.y) << 16);
    pm.y = (unsigned)f2bf(r * a.z + (1.f - r) * b.z) |
           ((unsigned)f2bf(r * a.w + (1.f - r) * b.w) << 16);
    x0b[i] = pa;
    xmb[i] = pm;
}

// ---------------------------------------------------------------------------
// prep_w: Wt[mat][n][k] for 6 mats (0-2 Wl, 3-5 Wr), then WoT[c][k] (48-pad)
// ---------------------------------------------------------------------------
static __global__ void prep_w_kernel(const float* __restrict__ Wl, const float* __restrict__ Wr,
                                     const float* __restrict__ Wout,
                                     unsigned short* __restrict__ Wt,
                                     unsigned short* __restrict__ WoT) {
    int t = blockIdx.x * blockDim.x + threadIdx.x;   // exactly 6*16384 + 48*128
    if (t < 6 * 16384) {
        int mat = t >> 14, idx = t & 16383;
        int n = idx >> 7, k = idx & 127;
        const float* src = (mat < 3) ? (Wl + mat * 16384) : (Wr + (mat - 3) * 16384);
        Wt[t] = f2bf(src[k * HID + n]);
    } else {
        int u = t - 6 * 16384;
        int c = u >> 7, k = u & 127;
        WoT[u] = (c < NCLS) ? f2bf(Wout[k * NCLS + c]) : (unsigned short)0;
    }
}

// ---------------------------------------------------------------------------
// spmm2: wave w<N -> S[w,:] = sum val[e]*y[colA[e],:]; w>=N -> T via B edges.
// Quarter-wave (16 lanes x 16B) per row gather, unroll x2 -> 8 rows in flight.
// ---------------------------------------------------------------------------
static __global__ __launch_bounds__(256) void spmm2_kernel(
    const unsigned short* __restrict__ y,
    const int* __restrict__ colA, const float* __restrict__ valA,
    const int* __restrict__ rpA, unsigned short* __restrict__ SA,
    const int* __restrict__ colB, const float* __restrict__ valB,
    const int* __restrict__ rpB, unsigned short* __restrict__ SB) {
    int w = blockIdx.x * 4 + (threadIdx.x >> 6);
    const int l = threadIdx.x & 63;
    const int q = l >> 4, j = l & 15;
    const int* col; const float* val; const int* rp; unsigned short* dst; int node;
    if (w < NNODES) { col = colA; val = valA; rp = rpA; dst = SA; node = w; }
    else            { col = colB; val = valB; rp = rpB; dst = SB; node = w - NNODES; }
    int e0 = rp[node], e1 = rp[node + 1];
    float a0 = 0.f, a1 = 0.f, a2 = 0.f, a3 = 0.f, a4 = 0.f, a5 = 0.f, a6 = 0.f, a7 = 0.f;
    int e = e0 + q;
    for (; e + 4 < e1; e += 8) {
        int c0 = col[e], c1 = col[e + 4];
        float v0 = val[e], v1 = val[e + 4];
        uint4 p0 = *(const uint4*)(y + (size_t)c0 * HID + j * 8);
        uint4 p1 = *(const uint4*)(y + (size_t)c1 * HID + j * 8);
        a0 = fmaf(v0, bflo(p0.x), a0); a1 = fmaf(v0, bfhi(p0.x), a1);
        a2 = fmaf(v0, bflo(p0.y), a2); a3 = fmaf(v0, bfhi(p0.y), a3);
        a4 = fmaf(v0, bflo(p0.z), a4); a5 = fmaf(v0, bfhi(p0.z), a5);
        a6 = fmaf(v0, bflo(p0.w), a6); a7 = fmaf(v0, bfhi(p0.w), a7);
        a0 = fmaf(v1, bflo(p1.x), a0); a1 = fmaf(v1, bfhi(p1.x), a1);
        a2 = fmaf(v1, bflo(p1.y), a2); a3 = fmaf(v1, bfhi(p1.y), a3);
        a4 = fmaf(v1, bflo(p1.z), a4); a5 = fmaf(v1, bfhi(p1.z), a5);
        a6 = fmaf(v1, bflo(p1.w), a6); a7 = fmaf(v1, bfhi(p1.w), a7);
    }
    if (e < e1) {
        int c0 = col[e];
        float v0 = val[e];
        uint4 p0 = *(const uint4*)(y + (size_t)c0 * HID + j * 8);
        a0 = fmaf(v0, bflo(p0.x), a0); a1 = fmaf(v0, bfhi(p0.x), a1);
        a2 = fmaf(v0, bflo(p0.y), a2); a3 = fmaf(v0, bfhi(p0.y), a3);
        a4 = fmaf(v0, bflo(p0.z), a4); a5 = fmaf(v0, bfhi(p0.z), a5);
        a6 = fmaf(v0, bflo(p0.w), a6); a7 = fmaf(v0, bfhi(p0.w), a7);
    }
    a0 += __shfl_xor(a0, 16); a1 += __shfl_xor(a1, 16);
    a2 += __shfl_xor(a2, 16); a3 += __shfl_xor(a3, 16);
    a4 += __shfl_xor(a4, 16); a5 += __shfl_xor(a5, 16);
    a6 += __shfl_xor(a6, 16); a7 += __shfl_xor(a7, 16);
    a0 += __shfl_xor(a0, 32); a1 += __shfl_xor(a1, 32);
    a2 += __shfl_xor(a2, 32); a3 += __shfl_xor(a3, 32);
    a4 += __shfl_xor(a4, 32); a5 += __shfl_xor(a5, 32);
    a6 += __shfl_xor(a6, 32); a7 += __shfl_xor(a7, 32);
    if (l < 16) {
        uint4 o;
        o.x = (unsigned)f2bf(a0) | ((unsigned)f2bf(a1) << 16);
        o.y = (unsigned)f2bf(a2) | ((unsigned)f2bf(a3) << 16);
        o.z = (unsigned)f2bf(a4) | ((unsigned)f2bf(a5) << 16);
        o.w = (unsigned)f2bf(a6) | ((unsigned)f2bf(a7) << 16);
        *(uint4*)(dst + (size_t)node * HID + l * 8) = o;
    }
}

// ---------------------------------------------------------------------------
// gemm_y: y = A @ Wt^T (bf16 out), output staged via LDS -> coalesced stores.
// A frag: row=lane&15, k=(lane>>4)*8+j. C: col=lane&15, row=(lane>>4)*4+reg.
// ---------------------------------------------------------------------------
static __global__ __launch_bounds__(256) void gemm_y_kernel(
    const unsigned short* __restrict__ A, const unsigned short* __restrict__ Wt,
    unsigned short* __restrict__ out) {
    __shared__ __align__(16) unsigned short ys[64][136];
    const int tid = threadIdx.x;
    const int lr = tid & 15;
    const int lg = (tid >> 4) & 3;
    const int wv = tid >> 6;
    const int gr0 = blockIdx.x * 64;
    const int arow = min(gr0 + wv * 16 + lr, NNODES - 1);
    const unsigned short* ap = A + (size_t)arow * HID + lg * 8;
    short8v a0 = *(const short8v*)(ap);
    short8v a1 = *(const short8v*)(ap + 32);
    short8v a2 = *(const short8v*)(ap + 64);
    short8v a3 = *(const short8v*)(ap + 96);
#pragma unroll
    for (int c = 0; c < 8; ++c) {
        const unsigned short* wp = Wt + (size_t)(c * 16 + lr) * HID + lg * 8;
        short8v b0 = *(const short8v*)(wp);
        short8v b1 = *(const short8v*)(wp + 32);
        short8v b2 = *(const short8v*)(wp + 64);
        short8v b3 = *(const short8v*)(wp + 96);
        float4v t = {0.f, 0.f, 0.f, 0.f};
        t = __builtin_amdgcn_mfma_f32_16x16x32_bf16(a0, b0, t, 0, 0, 0);
        t = __builtin_amdgcn_mfma_f32_16x16x32_bf16(a1, b1, t, 0, 0, 0);
        t = __builtin_amdgcn_mfma_f32_16x16x32_bf16(a2, b2, t, 0, 0, 0);
        t = __builtin_amdgcn_mfma_f32_16x16x32_bf16(a3, b3, t, 0, 0, 0);
#pragma unroll
        for (int r = 0; r < 4; ++r) ys[wv * 16 + lg * 4 + r][c * 16 + lr] = f2bf(t[r]);
    }
    __syncthreads();
#pragma unroll
    for (int i = 0; i < 4; ++i) {
        int flat = tid * 8 + i * 2048;
        int row = flat >> 7, colv = flat & 127;
        int m = gr0 + row;
        if (m < NNODES)
            *(uint4*)(out + (size_t)m * HID + colv) = *(const uint4*)&ys[row][colv];
    }
}

// ---------------------------------------------------------------------------
// fused_layer<DO_HY>: all tile IO coalesced via LDS.
//   z = xm @ Wr + b; DO_HY: hv = relu(S + Ah@Wr + b)
//   xm' = r*relu(S+z) + (1-r)*relu(T+z)
//   DO_HY:  xm'->Sls, hv->hs; y' = h @ WtLn -> Tls; coalesced stores of all 3
//   !DO_HY: xm'->hs; head MFMA with WoT; log_softmax -> out
// ---------------------------------------------------------------------------
template <bool DO_HY>
static __global__ __launch_bounds__(256) void fused_layer_kernel(
    const unsigned short* __restrict__ Ah,
    const unsigned short* xmIn,
    const unsigned short* __restrict__ WtR,
    const unsigned short* __restrict__ WtLn,
    const unsigned short* __restrict__ S,
    const unsigned short* __restrict__ T,
    const float* __restrict__ bias,
    const float* __restrict__ mixr,
    unsigned short* __restrict__ hOut,
    unsigned short* __restrict__ yOut,
    unsigned short* xmOut,
    const unsigned short* __restrict__ WoT,
    const float* __restrict__ bout,
    float* __restrict__ out) {
    __shared__ __align__(16) unsigned short Sls[64][136];
    __shared__ __align__(16) unsigned short Tls[64][136];
    __shared__ __align__(16) unsigned short hs[64][136];
    const int tid = threadIdx.x;
    const int lr = tid & 15;
    const int lg = (tid >> 4) & 3;
    const int wv = tid >> 6;
    const int gr0 = blockIdx.x * 64;
    const float rr = mixr[0];

    // ---- issue coalesced S/T tile loads early (overrun past N stays in d_ws)
    uint4 sreg[4], treg[4];
#pragma unroll
    for (int i = 0; i < 4; ++i) {
        int flat = tid * 8 + i * 2048;
        int row = flat >> 7, colv = flat & 127;
        size_t g = (size_t)(gr0 + row) * HID + colv;
        sreg[i] = *(const uint4*)(S + g);
        treg[i] = *(const uint4*)(T + g);
    }

    // ---- A fragments
    const int arow = min(gr0 + wv * 16 + lr, NNODES - 1);
    const unsigned short* xp = xmIn + (size_t)arow * HID + lg * 8;
    short8v ax0 = *(const short8v*)(xp);
    short8v ax1 = *(const short8v*)(xp + 32);
    short8v ax2 = *(const short8v*)(xp + 64);
    short8v ax3 = *(const short8v*)(xp + 96);
    short8v ah0, ah1, ah2, ah3;
    if constexpr (DO_HY) {
        const unsigned short* hp = Ah + (size_t)arow * HID + lg * 8;
        ah0 = *(const short8v*)(hp);
        ah1 = *(const short8v*)(hp + 32);
        ah2 = *(const short8v*)(hp + 64);
        ah3 = *(const short8v*)(hp + 96);
    }

    // ---- dual MFMA core (shared B fragments)
    float4v accz[8], acch[8];
#pragma unroll
    for (int c = 0; c < 8; ++c) {
        const unsigned short* wp = WtR + (size_t)(c * 16 + lr) * HID + lg * 8;
        short8v b0 = *(const short8v*)(wp);
        short8v b1 = *(const short8v*)(wp + 32);
        short8v b2 = *(const short8v*)(wp + 64);
        short8v b3 = *(const short8v*)(wp + 96);
        float4v t = {0.f, 0.f, 0.f, 0.f};
        t = __builtin_amdgcn_mfma_f32_16x16x32_bf16(ax0, b0, t, 0, 0, 0);
        t = __builtin_amdgcn_mfma_f32_16x16x32_bf16(ax1, b1, t, 0, 0, 0);
        t = __builtin_amdgcn_mfma_f32_16x16x32_bf16(ax2, b2, t, 0, 0, 0);
        t = __builtin_amdgcn_mfma_f32_16x16x32_bf16(ax3, b3, t, 0, 0, 0);
        accz[c] = t;
        if constexpr (DO_HY) {
            float4v u = {0.f, 0.f, 0.f, 0.f};
            u = __builtin_amdgcn_mfma_f32_16x16x32_bf16(ah0, b0, u, 0, 0, 0);
            u = __builtin_amdgcn_mfma_f32_16x16x32_bf16(ah1, b1, u, 0, 0, 0);
            u = __builtin_amdgcn_mfma_f32_16x16x32_bf16(ah2, b2, u, 0, 0, 0);
            u = __builtin_amdgcn_mfma_f32_16x16x32_bf16(ah3, b3, u, 0, 0, 0);
            acch[c] = u;
        }
    }

    // ---- stage S/T into LDS
#pragma unroll
    for (int i = 0; i < 4; ++i) {
        int flat = tid * 8 + i * 2048;
        int row = flat >> 7, colv = flat & 127;
        *(uint4*)&Sls[row][colv] = sreg[i];
        *(uint4*)&Tls[row][colv] = treg[i];
    }
    __syncthreads();

    // ---- epilogue in fragment layout (LDS only)
#pragma unroll
    for (int c = 0; c < 8; ++c) {
        const int colc = c * 16 + lr;
        const float bv = bias[colc];
#pragma unroll
        for (int r = 0; r < 4; ++r) {
            const int lrow = wv * 16 + lg * 4 + r;
            const float sv = bf2f(Sls[lrow][colc]);
            const float tv = bf2f(Tls[lrow][colc]);
            const float z = accz[c][r] + bv;
            const float xa = fmaxf(sv + z, 0.f);
            const float xb = fmaxf(tv + z, 0.f);
            const unsigned short xmv = f2bf(rr * xa + (1.f - rr) * xb);
            if constexpr (DO_HY) {
                hs[lrow][colc] = f2bf(fmaxf(acch[c][r] + sv + bv, 0.f));
                Sls[lrow][colc] = xmv;   // same-slot overwrite by same thread: safe
            } else {
                hs[lrow][colc] = xmv;
            }
        }
    }
    __syncthreads();

    if constexpr (DO_HY) {
        // ---- coalesced stores: xm (Sls), h (hs)
#pragma unroll
        for (int i = 0; i < 4; ++i) {
            int flat = tid * 8 + i * 2048;
            int row = flat >> 7, colv = flat & 127;
            int m = gr0 + row;
            if (m < NNODES) {
                *(uint4*)(xmOut + (size_t)m * HID + colv) = *(const uint4*)&Sls[row][colv];
                *(uint4*)(hOut + (size_t)m * HID + colv) = *(const uint4*)&hs[row][colv];
            }
        }
        // ---- stage 2: y = h @ WtLn (A frags from LDS, same-wave stripe)
        const unsigned short* lp = &hs[wv * 16 + lr][lg * 8];
        short8v c0 = *(const short8v*)(lp);
        short8v c1 = *(const short8v*)(lp + 32);
        short8v c2 = *(const short8v*)(lp + 64);
        short8v c3 = *(const short8v*)(lp + 96);
#pragma unroll
        for (int c = 0; c < 8; ++c) {
            const unsigned short* wp = WtLn + (size_t)(c * 16 + lr) * HID + lg * 8;
            short8v b0 = *(const short8v*)(wp);
            short8v b1 = *(const short8v*)(wp + 32);
            short8v b2 = *(const short8v*)(wp + 64);
            short8v b3 = *(const short8v*)(wp + 96);
            float4v t = {0.f, 0.f, 0.f, 0.f};
            t = __builtin_amdgcn_mfma_f32_16x16x32_bf16(c0, b0, t, 0, 0, 0);
            t = __builtin_amdgcn_mfma_f32_16x16x32_bf16(c1, b1, t, 0, 0, 0);
            t = __builtin_amdgcn_mfma_f32_16x16x32_bf16(c2, b2, t, 0, 0, 0);
            t = __builtin_amdgcn_mfma_f32_16x16x32_bf16(c3, b3, t, 0, 0, 0);
#pragma unroll
            for (int r = 0; r < 4; ++r)
                Tls[wv * 16 + lg * 4 + r][c * 16 + lr] = f2bf(t[r]);
        }
        __syncthreads();
#pragma unroll
        for (int i = 0; i < 4; ++i) {
            int flat = tid * 8 + i * 2048;
            int row = flat >> 7, colv = flat & 127;
            int m = gr0 + row;
            if (m < NNODES)
                *(uint4*)(yOut + (size_t)m * HID + colv) = *(const uint4*)&Tls[row][colv];
        }
    } else {
        // ---- head: logits = xm' @ WoT + bout; log_softmax
        const unsigned short* lp = &hs[wv * 16 + lr][lg * 8];
        short8v c0 = *(const short8v*)(lp);
        short8v c1 = *(const short8v*)(lp + 32);
        short8v c2 = *(const short8v*)(lp + 64);
        short8v c3 = *(const short8v*)(lp + 96);
        float4v acc[3];
#pragma unroll
        for (int c = 0; c < 3; ++c) {
            const unsigned short* wp = WoT + (size_t)(c * 16 + lr) * HID + lg * 8;
            short8v b0 = *(const short8v*)(wp);
            short8v b1 = *(const short8v*)(wp + 32);
            short8v b2 = *(const short8v*)(wp + 64);
            short8v b3 = *(const short8v*)(wp + 96);
            float4v t = {0.f, 0.f, 0.f, 0.f};
            t = __builtin_amdgcn_mfma_f32_16x16x32_bf16(c0, b0, t, 0, 0, 0);
            t = __builtin_amdgcn_mfma_f32_16x16x32_bf16(c1, b1, t, 0, 0, 0);
            t = __builtin_amdgcn_mfma_f32_16x16x32_bf16(c2, b2, t, 0, 0, 0);
            t = __builtin_amdgcn_mfma_f32_16x16x32_bf16(c3, b3, t, 0, 0, 0);
            acc[c] = t;
        }
        const float bia0 = bout[lr];
        const float bia1 = bout[16 + lr];
        const float bia2 = (lr < 8) ? bout[32 + lr] : 0.f;
#pragma unroll
        for (int r = 0; r < 4; ++r) {
            float l0 = acc[0][r] + bia0;
            float l1 = acc[1][r] + bia1;
            float l2 = (lr < 8) ? (acc[2][r] + bia2) : -INFINITY;
            float mx = fmaxf(fmaxf(l0, l1), l2);
#pragma unroll
            for (int off = 1; off < 16; off <<= 1) mx = fmaxf(mx, __shfl_xor(mx, off));
            float s = expf(l0 - mx) + expf(l1 - mx) + ((lr < 8) ? expf(l2 - mx) : 0.f);
#pragma unroll
            for (int off = 1; off < 16; off <<= 1) s += __shfl_xor(s, off);
            float lse = mx + logf(s);
            int m = gr0 + wv * 16 + lg * 4 + r;
            if (m < NNODES) {
                out[(size_t)m * NCLS + lr] = l0 - lse;
                out[(size_t)m * NCLS + 16 + lr] = l1 - lse;
                if (lr < 8) out[(size_t)m * NCLS + 32 + lr] = l2 - lse;
            }
        }
    }
}

// ---------------------------------------------------------------------------
extern "C" void kernel_launch(void* const* d_in, const int* in_sizes, int n_in,
                              void* d_out, int out_size, void* d_ws, size_t ws_size,
                              hipStream_t stream) {
    const float* x0   = (const float*)d_in[0];
    const int*   arow = (const int*)d_in[1];
    const int*   acol = (const int*)d_in[2];
    const float* aval = (const float*)d_in[3];
    const int*   brow = (const int*)d_in[4];
    const int*   bcol = (const int*)d_in[5];
    const float* bval = (const float*)d_in[6];
    const float* mixr = (const float*)d_in[7];
    const int*   id   = (const int*)d_in[8];
    const float* Wl   = (const float*)d_in[9];
    const float* Wr   = (const float*)d_in[10];
    const float* bs   = (const float*)d_in[11];
    const float* Wout = (const float*)d_in[12];
    const float* bout = (const float*)d_in[13];
    float* out = (float*)d_out;

    const size_t NF = (size_t)NNODES * HID;   // 6.4M
    unsigned short* x0b = (unsigned short*)d_ws;
    unsigned short* xmb = x0b + NF;
    unsigned short* h1b = xmb + NF;
    unsigned short* h2b = h1b + NF;
    unsigned short* yb  = h2b + NF;
    unsigned short* S   = yb + NF;
    unsigned short* T   = S + NF;
    unsigned short* Wt  = T + NF;             // 6 * 16384 bf16
    unsigned short* WoT = Wt + 6 * 16384;     // 48 * 128 bf16
    int* rpa = (int*)(WoT + 48 * 128);
    int* rpb = rpa + (NNODES + 1);
    int* bcol2 = rpb + (NNODES + 1);

    const int gE = (NEDGES + 255) / 256;      // 1954
    const int gC = NNODES * HID / 4 / 256;    // 6250
    const int gG = (NNODES + 63) / 64;        // 782
    const int gS2 = 2 * NNODES * 64 / 256;    // 25000

    prep_edges_kernel<<<3 * gE, 256, 0, stream>>>(arow, brow, bcol, id, rpa, rpb, bcol2, gE);
    prep_x_kernel<<<gC, 256, 0, stream>>>((const float4*)x0, id, mixr, (uint2*)x0b, (uint2*)xmb);
    prep_w_kernel<<<(6 * 16384 + 48 * 128) / 256, 256, 0, stream>>>(Wl, Wr, Wout, Wt, WoT);

    // y0 = x0 @ Wl0
    gemm_y_kernel<<<gG, 256, 0, stream>>>(x0b, Wt + 0 * 16384, yb);

    // ---- layer 0
    spmm2_kernel<<<gS2, 256, 0, stream>>>(yb, acol, aval, rpa, S, bcol2, bval, rpb, T);
    fused_layer_kernel<true><<<gG, 256, 0, stream>>>(
        x0b, xmb, Wt + 3 * 16384, Wt + 1 * 16384, S, T, bs, mixr,
        h1b, yb, xmb, nullptr, nullptr, nullptr);

    // ---- layer 1
    spmm2_kernel<<<gS2, 256, 0, stream>>>(yb, acol, aval, rpa, S, bcol2, bval, rpb, T);
    fused_layer_kernel<true><<<gG, 256, 0, stream>>>(
        h1b, xmb, Wt + 4 * 16384, Wt + 2 * 16384, S, T, bs + 128, mixr,
        h2b, yb, xmb, nullptr, nullptr, nullptr);

    // ---- layer 2 (+ head)
    spmm2_kernel<<<gS2, 256, 0, stream>>>(yb, acol, aval, rpa, S, bcol2, bval, rpb, T);
    fused_layer_kernel<false><<<gG, 256, 0, stream>>>(
        h2b, xmb, Wt + 5 * 16384, nullptr, S, T, bs + 256, mixr,
        nullptr, nullptr, nullptr, WoT, bout, out);
}

// Round 6
// 271.821 us; speedup vs baseline: 3.6489x; 1.0674x over previous
//
#include <hip/hip_runtime.h>
#include <math.h>

#define NNODES 50000
#define NEDGES 500000
#define HID 128
#define NCLS 40

using short8v = __attribute__((ext_vector_type(8))) short;
using float4v = __attribute__((ext_vector_type(4))) float;

static __device__ __forceinline__ unsigned short f2bf(float f) {
    unsigned int u = __float_as_uint(f);
    u += 0x7FFFu + ((u >> 16) & 1u);   // RNE
    return (unsigned short)(u >> 16);
}
static __device__ __forceinline__ float bf2f(unsigned short h) {
    return __uint_as_float(((unsigned int)h) << 16);
}
static __device__ __forceinline__ float bflo(unsigned int p) {
    return __uint_as_float(p << 16);
}
static __device__ __forceinline__ float bfhi(unsigned int p) {
    return __uint_as_float(p & 0xFFFF0000u);
}

// ---------------------------------------------------------------------------
// prep_edges: [0,gE) rowptr A; [gE,2gE) rowptr B; [2gE,3gE) bcol2 = id[bcol]
// ---------------------------------------------------------------------------
static __device__ __forceinline__ void rowptr_body(const int* __restrict__ row,
                                                   int e, int* __restrict__ rp) {
    if (e >= NEDGES) return;
    int r = row[e];
    int prev = (e == 0) ? -1 : row[e - 1];
    for (int q = prev + 1; q <= r; ++q) rp[q] = e;
    if (e == NEDGES - 1) {
        for (int q = r + 1; q <= NNODES; ++q) rp[q] = NEDGES;
    }
}

static __global__ void prep_edges_kernel(const int* __restrict__ arow,
                                         const int* __restrict__ brow,
                                         const int* __restrict__ bcol,
                                         const int* __restrict__ id,
                                         int* __restrict__ rpa, int* __restrict__ rpb,
                                         int* __restrict__ bcol2, int gE) {
    int bid = blockIdx.x;
    if (bid < gE) {
        rowptr_body(arow, bid * 256 + threadIdx.x, rpa);
    } else if (bid < 2 * gE) {
        rowptr_body(brow, (bid - gE) * 256 + threadIdx.x, rpb);
    } else {
        int e = (bid - 2 * gE) * 256 + threadIdx.x;
        if (e < NEDGES) bcol2[e] = id[bcol[e]];
    }
}

// ---------------------------------------------------------------------------
// prep_x: x0b = bf16(x0); xmb = bf16(r*x0 + (1-r)*x0[id])
// ---------------------------------------------------------------------------
static __global__ void prep_x_kernel(const float4* __restrict__ x, const int* __restrict__ id,
                                     const float* __restrict__ mixr,
                                     uint2* __restrict__ x0b, uint2* xmb) {
    int i = blockIdx.x * blockDim.x + threadIdx.x;   // exactly N*HID/4
    int n = i >> 5, qq = i & 31;
    float r = mixr[0];
    float4 a = x[i];
    float4 b = x[(size_t)id[n] * 32 + qq];
    uint2 pa, pm;
    pa.x = (unsigned)f2bf(a.x) | ((unsigned)f2bf(a.y) << 16);
    pa.y = (unsigned)f2bf(a.z) | ((unsigned)f2bf(a.w) << 16);
    pm.x = (unsigned)f2bf(r * a.x + (1.f - r) * b.x) |
           ((unsigned)f2bf(r * a.y + (1.f - r) * b.y) << 16);
    pm.y = (unsigned)f2bf(r * a.z + (1.f - r) * b.z) |
           ((unsigned)f2bf(r * a.w + (1.f - r) * b.w) << 16);
    x0b[i] = pa;
    xmb[i] = pm;
}

// ---------------------------------------------------------------------------
// prep_w: Wt[mat][n][k] for 6 mats (0-2 Wl, 3-5 Wr), then WoT[c][k] (48-pad)
// ---------------------------------------------------------------------------
static __global__ void prep_w_kernel(const float* __restrict__ Wl, const float* __restrict__ Wr,
                                     const float* __restrict__ Wout,
                                     unsigned short* __restrict__ Wt,
                                     unsigned short* __restrict__ WoT) {
    int t = blockIdx.x * blockDim.x + threadIdx.x;   // exactly 6*16384 + 48*128
    if (t < 6 * 16384) {
        int mat = t >> 14, idx = t & 16383;
        int n = idx >> 7, k = idx & 127;
        const float* src = (mat < 3) ? (Wl + mat * 16384) : (Wr + (mat - 3) * 16384);
        Wt[t] = f2bf(src[k * HID + n]);
    } else {
        int u = t - 6 * 16384;
        int c = u >> 7, k = u & 127;
        WoT[u] = (c < NCLS) ? f2bf(Wout[k * NCLS + c]) : (unsigned short)0;
    }
}

// ---------------------------------------------------------------------------
// spmm2: wave w<N -> S[w,:] = sum val[e]*y[colA[e],:]; w>=N -> T via B edges.
// Quarter-wave (16 lanes x 16B) per row gather, unroll x2 -> 8 rows in flight.
// ---------------------------------------------------------------------------
static __global__ __launch_bounds__(256) void spmm2_kernel(
    const unsigned short* __restrict__ y,
    const int* __restrict__ colA, const float* __restrict__ valA,
    const int* __restrict__ rpA, unsigned short* __restrict__ SA,
    const int* __restrict__ colB, const float* __restrict__ valB,
    const int* __restrict__ rpB, unsigned short* __restrict__ SB) {
    int w = blockIdx.x * 4 + (threadIdx.x >> 6);
    const int l = threadIdx.x & 63;
    const int q = l >> 4, j = l & 15;
    const int* col; const float* val; const int* rp; unsigned short* dst; int node;
    if (w < NNODES) { col = colA; val = valA; rp = rpA; dst = SA; node = w; }
    else            { col = colB; val = valB; rp = rpB; dst = SB; node = w - NNODES; }
    int e0 = rp[node], e1 = rp[node + 1];
    float a0 = 0.f, a1 = 0.f, a2 = 0.f, a3 = 0.f, a4 = 0.f, a5 = 0.f, a6 = 0.f, a7 = 0.f;
    int e = e0 + q;
    for (; e + 4 < e1; e += 8) {
        int c0 = col[e], c1 = col[e + 4];
        float v0 = val[e], v1 = val[e + 4];
        uint4 p0 = *(const uint4*)(y + (size_t)c0 * HID + j * 8);
        uint4 p1 = *(const uint4*)(y + (size_t)c1 * HID + j * 8);
        a0 = fmaf(v0, bflo(p0.x), a0); a1 = fmaf(v0, bfhi(p0.x), a1);
        a2 = fmaf(v0, bflo(p0.y), a2); a3 = fmaf(v0, bfhi(p0.y), a3);
        a4 = fmaf(v0, bflo(p0.z), a4); a5 = fmaf(v0, bfhi(p0.z), a5);
        a6 = fmaf(v0, bflo(p0.w), a6); a7 = fmaf(v0, bfhi(p0.w), a7);
        a0 = fmaf(v1, bflo(p1.x), a0); a1 = fmaf(v1, bfhi(p1.x), a1);
        a2 = fmaf(v1, bflo(p1.y), a2); a3 = fmaf(v1, bfhi(p1.y), a3);
        a4 = fmaf(v1, bflo(p1.z), a4); a5 = fmaf(v1, bfhi(p1.z), a5);
        a6 = fmaf(v1, bflo(p1.w), a6); a7 = fmaf(v1, bfhi(p1.w), a7);
    }
    if (e < e1) {
        int c0 = col[e];
        float v0 = val[e];
        uint4 p0 = *(const uint4*)(y + (size_t)c0 * HID + j * 8);
        a0 = fmaf(v0, bflo(p0.x), a0); a1 = fmaf(v0, bfhi(p0.x), a1);
        a2 = fmaf(v0, bflo(p0.y), a2); a3 = fmaf(v0, bfhi(p0.y), a3);
        a4 = fmaf(v0, bflo(p0.z), a4); a5 = fmaf(v0, bfhi(p0.z), a5);
        a6 = fmaf(v0, bflo(p0.w), a6); a7 = fmaf(v0, bfhi(p0.w), a7);
    }
    a0 += __shfl_xor(a0, 16); a1 += __shfl_xor(a1, 16);
    a2 += __shfl_xor(a2, 16); a3 += __shfl_xor(a3, 16);
    a4 += __shfl_xor(a4, 16); a5 += __shfl_xor(a5, 16);
    a6 += __shfl_xor(a6, 16); a7 += __shfl_xor(a7, 16);
    a0 += __shfl_xor(a0, 32); a1 += __shfl_xor(a1, 32);
    a2 += __shfl_xor(a2, 32); a3 += __shfl_xor(a3, 32);
    a4 += __shfl_xor(a4, 32); a5 += __shfl_xor(a5, 32);
    a6 += __shfl_xor(a6, 32); a7 += __shfl_xor(a7, 32);
    if (l < 16) {
        uint4 o;
        o.x = (unsigned)f2bf(a0) | ((unsigned)f2bf(a1) << 16);
        o.y = (unsigned)f2bf(a2) | ((unsigned)f2bf(a3) << 16);
        o.z = (unsigned)f2bf(a4) | ((unsigned)f2bf(a5) << 16);
        o.w = (unsigned)f2bf(a6) | ((unsigned)f2bf(a7) << 16);
        *(uint4*)(dst + (size_t)node * HID + l * 8) = o;
    }
}

// ---------------------------------------------------------------------------
// Swapped-operand MFMA: acc = mfma(Wfrag, Xfrag) computes D^T, giving layout
//   D[row = r0 + (lane&15)][col = c*16 + (lane>>4)*4 + i], i = reg 0..3
// -> lane owns 4 CONSECUTIVE cols of its own row: uint2 global IO, no LDS.
// One wave per 16 rows; N/16 = 3125 blocks exactly (no bounds checks).
// ---------------------------------------------------------------------------
static __global__ __launch_bounds__(64) void gemm_y_kernel(
    const unsigned short* __restrict__ A, const unsigned short* __restrict__ Wt,
    unsigned short* __restrict__ out) {
    const int lr = threadIdx.x & 15;
    const int lg = threadIdx.x >> 4;
    const int row = blockIdx.x * 16 + lr;
    const unsigned short* ap = A + (size_t)row * HID + lg * 8;
    short8v a0 = *(const short8v*)(ap);
    short8v a1 = *(const short8v*)(ap + 32);
    short8v a2 = *(const short8v*)(ap + 64);
    short8v a3 = *(const short8v*)(ap + 96);
#pragma unroll
    for (int c = 0; c < 8; ++c) {
        const unsigned short* wp = Wt + (size_t)(c * 16 + lr) * HID + lg * 8;
        short8v b0 = *(const short8v*)(wp);
        short8v b1 = *(const short8v*)(wp + 32);
        short8v b2 = *(const short8v*)(wp + 64);
        short8v b3 = *(const short8v*)(wp + 96);
        float4v t = {0.f, 0.f, 0.f, 0.f};
        t = __builtin_amdgcn_mfma_f32_16x16x32_bf16(b0, a0, t, 0, 0, 0);
        t = __builtin_amdgcn_mfma_f32_16x16x32_bf16(b1, a1, t, 0, 0, 0);
        t = __builtin_amdgcn_mfma_f32_16x16x32_bf16(b2, a2, t, 0, 0, 0);
        t = __builtin_amdgcn_mfma_f32_16x16x32_bf16(b3, a3, t, 0, 0, 0);
        uint2 o;
        o.x = (unsigned)f2bf(t[0]) | ((unsigned)f2bf(t[1]) << 16);
        o.y = (unsigned)f2bf(t[2]) | ((unsigned)f2bf(t[3]) << 16);
        *(uint2*)(out + (size_t)row * HID + c * 16 + lg * 4) = o;
    }
}

// ---------------------------------------------------------------------------
// fused_layer<DO_HY>, one wave per 16 rows, swapped layout:
//   z = xm @ Wr + b;  DO_HY: hv = relu(S + Ah@Wr + b)
//   xm' = r*relu(S+z) + (1-r)*relu(T+z)
//   DO_HY:  store xm',h (uint2); h->LDS; y' = h @ WtLn -> uint2 stores
//   !DO_HY: xm'->LDS; head: logits = xm' @ WoT + bout; log_softmax -> out
// ---------------------------------------------------------------------------
template <bool DO_HY>
static __global__ __launch_bounds__(64) void fused_layer_kernel(
    const unsigned short* __restrict__ Ah,
    const unsigned short* xmIn,
    const unsigned short* __restrict__ WtR,
    const unsigned short* __restrict__ WtLn,
    const unsigned short* __restrict__ S,
    const unsigned short* __restrict__ T,
    const float* __restrict__ bias,
    const float* __restrict__ mixr,
    unsigned short* __restrict__ hOut,
    unsigned short* __restrict__ yOut,
    unsigned short* xmOut,
    const unsigned short* __restrict__ WoT,
    const float* __restrict__ bout,
    float* __restrict__ out) {
    __shared__ __align__(16) unsigned short hs[16][136];
    const int lr = threadIdx.x & 15;
    const int lg = threadIdx.x >> 4;
    const int row = blockIdx.x * 16 + lr;
    const float rr = mixr[0];

    // ---- A-operand (= X) fragments
    const unsigned short* xp = xmIn + (size_t)row * HID + lg * 8;
    short8v ax0 = *(const short8v*)(xp);
    short8v ax1 = *(const short8v*)(xp + 32);
    short8v ax2 = *(const short8v*)(xp + 64);
    short8v ax3 = *(const short8v*)(xp + 96);
    short8v ah0, ah1, ah2, ah3;
    if constexpr (DO_HY) {
        const unsigned short* hp = Ah + (size_t)row * HID + lg * 8;
        ah0 = *(const short8v*)(hp);
        ah1 = *(const short8v*)(hp + 32);
        ah2 = *(const short8v*)(hp + 64);
        ah3 = *(const short8v*)(hp + 96);
    }

    // ---- dual MFMA core (shared W fragments), swapped operands
    float4v accz[8], acch[8];
#pragma unroll
    for (int c = 0; c < 8; ++c) {
        const unsigned short* wp = WtR + (size_t)(c * 16 + lr) * HID + lg * 8;
        short8v b0 = *(const short8v*)(wp);
        short8v b1 = *(const short8v*)(wp + 32);
        short8v b2 = *(const short8v*)(wp + 64);
        short8v b3 = *(const short8v*)(wp + 96);
        float4v t = {0.f, 0.f, 0.f, 0.f};
        t = __builtin_amdgcn_mfma_f32_16x16x32_bf16(b0, ax0, t, 0, 0, 0);
        t = __builtin_amdgcn_mfma_f32_16x16x32_bf16(b1, ax1, t, 0, 0, 0);
        t = __builtin_amdgcn_mfma_f32_16x16x32_bf16(b2, ax2, t, 0, 0, 0);
        t = __builtin_amdgcn_mfma_f32_16x16x32_bf16(b3, ax3, t, 0, 0, 0);
        accz[c] = t;
        if constexpr (DO_HY) {
            float4v u = {0.f, 0.f, 0.f, 0.f};
            u = __builtin_amdgcn_mfma_f32_16x16x32_bf16(b0, ah0, u, 0, 0, 0);
            u = __builtin_amdgcn_mfma_f32_16x16x32_bf16(b1, ah1, u, 0, 0, 0);
            u = __builtin_amdgcn_mfma_f32_16x16x32_bf16(b2, ah2, u, 0, 0, 0);
            u = __builtin_amdgcn_mfma_f32_16x16x32_bf16(b3, ah3, u, 0, 0, 0);
            acch[c] = u;
        }
    }

    // ---- epilogue: direct uint2 global IO, no LDS staging of S/T
#pragma unroll
    for (int c = 0; c < 8; ++c) {
        const int col0 = c * 16 + lg * 4;
        const size_t g = (size_t)row * HID + col0;
        const uint2 sv = *(const uint2*)(S + g);
        const uint2 tv = *(const uint2*)(T + g);
        const float4v bv = *(const float4v*)(bias + col0);
        const float s4[4] = {bflo(sv.x), bfhi(sv.x), bflo(sv.y), bfhi(sv.y)};
        const float t4[4] = {bflo(tv.x), bfhi(tv.x), bflo(tv.y), bfhi(tv.y)};
        unsigned short xm4[4], h4[4];
#pragma unroll
        for (int i = 0; i < 4; ++i) {
            const float z = accz[c][i] + bv[i];
            const float xa = fmaxf(s4[i] + z, 0.f);
            const float xb = fmaxf(t4[i] + z, 0.f);
            xm4[i] = f2bf(rr * xa + (1.f - rr) * xb);
            if constexpr (DO_HY) h4[i] = f2bf(fmaxf(acch[c][i] + s4[i] + bv[i], 0.f));
        }
        uint2 xmv;
        xmv.x = (unsigned)xm4[0] | ((unsigned)xm4[1] << 16);
        xmv.y = (unsigned)xm4[2] | ((unsigned)xm4[3] << 16);
        if constexpr (DO_HY) {
            uint2 hv;
            hv.x = (unsigned)h4[0] | ((unsigned)h4[1] << 16);
            hv.y = (unsigned)h4[2] | ((unsigned)h4[3] << 16);
            *(uint2*)(xmOut + g) = xmv;
            *(uint2*)(hOut + g) = hv;
            *(uint2*)(&hs[lr][col0]) = hv;
        } else {
            *(uint2*)(&hs[lr][col0]) = xmv;
        }
    }
    __syncthreads();

    // ---- stage 2: A-frags (X-operand) from LDS tile
    const unsigned short* lp = &hs[lr][lg * 8];
    short8v c0 = *(const short8v*)(lp);
    short8v c1 = *(const short8v*)(lp + 32);
    short8v c2 = *(const short8v*)(lp + 64);
    short8v c3 = *(const short8v*)(lp + 96);

    if constexpr (DO_HY) {
        // y = h @ WtLn
#pragma unroll
        for (int c = 0; c < 8; ++c) {
            const unsigned short* wp = WtLn + (size_t)(c * 16 + lr) * HID + lg * 8;
            short8v b0 = *(const short8v*)(wp);
            short8v b1 = *(const short8v*)(wp + 32);
            short8v b2 = *(const short8v*)(wp + 64);
            short8v b3 = *(const short8v*)(wp + 96);
            float4v t = {0.f, 0.f, 0.f, 0.f};
            t = __builtin_amdgcn_mfma_f32_16x16x32_bf16(b0, c0, t, 0, 0, 0);
            t = __builtin_amdgcn_mfma_f32_16x16x32_bf16(b1, c1, t, 0, 0, 0);
            t = __builtin_amdgcn_mfma_f32_16x16x32_bf16(b2, c2, t, 0, 0, 0);
            t = __builtin_amdgcn_mfma_f32_16x16x32_bf16(b3, c3, t, 0, 0, 0);
            uint2 o;
            o.x = (unsigned)f2bf(t[0]) | ((unsigned)f2bf(t[1]) << 16);
            o.y = (unsigned)f2bf(t[2]) | ((unsigned)f2bf(t[3]) << 16);
            *(uint2*)(yOut + (size_t)row * HID + c * 16 + lg * 4) = o;
        }
    } else {
        // head: logits = xm' @ WoT + bout (lane: row=lr fixed; cols c*16+lg*4+i)
        float lv[3][4];
        float mx = -INFINITY;
#pragma unroll
        for (int c = 0; c < 3; ++c) {
            const unsigned short* wp = WoT + (size_t)(c * 16 + lr) * HID + lg * 8;
            short8v b0 = *(const short8v*)(wp);
            short8v b1 = *(const short8v*)(wp + 32);
            short8v b2 = *(const short8v*)(wp + 64);
            short8v b3 = *(const short8v*)(wp + 96);
            float4v t = {0.f, 0.f, 0.f, 0.f};
            t = __builtin_amdgcn_mfma_f32_16x16x32_bf16(b0, c0, t, 0, 0, 0);
            t = __builtin_amdgcn_mfma_f32_16x16x32_bf16(b1, c1, t, 0, 0, 0);
            t = __builtin_amdgcn_mfma_f32_16x16x32_bf16(b2, c2, t, 0, 0, 0);
            t = __builtin_amdgcn_mfma_f32_16x16x32_bf16(b3, c3, t, 0, 0, 0);
            const int col0 = c * 16 + lg * 4;
            const bool valid = col0 < NCLS;
#pragma unroll
            for (int i = 0; i < 4; ++i) {
                const float l = valid ? (t[i] + bout[col0 + i]) : -INFINITY;
                lv[c][i] = l;
                mx = fmaxf(mx, l);
            }
        }
        mx = fmaxf(mx, __shfl_xor(mx, 16));
        mx = fmaxf(mx, __shfl_xor(mx, 32));
        float sum = 0.f;
#pragma unroll
        for (int c = 0; c < 3; ++c)
#pragma unroll
            for (int i = 0; i < 4; ++i)
                if (lv[c][i] > -INFINITY) sum += expf(lv[c][i] - mx);
        sum += __shfl_xor(sum, 16);
        sum += __shfl_xor(sum, 32);
        const float lse = mx + logf(sum);
#pragma unroll
        for (int c = 0; c < 3; ++c) {
            const int col0 = c * 16 + lg * 4;
            if (col0 < NCLS) {
                float4 o = make_float4(lv[c][0] - lse, lv[c][1] - lse,
                                       lv[c][2] - lse, lv[c][3] - lse);
                *(float4*)(out + (size_t)row * NCLS + col0) = o;
            }
        }
    }
}

// ---------------------------------------------------------------------------
extern "C" void kernel_launch(void* const* d_in, const int* in_sizes, int n_in,
                              void* d_out, int out_size, void* d_ws, size_t ws_size,
                              hipStream_t stream) {
    const float* x0   = (const float*)d_in[0];
    const int*   arow = (const int*)d_in[1];
    const int*   acol = (const int*)d_in[2];
    const float* aval = (const float*)d_in[3];
    const int*   brow = (const int*)d_in[4];
    const int*   bcol = (const int*)d_in[5];
    const float* bval = (const float*)d_in[6];
    const float* mixr = (const float*)d_in[7];
    const int*   id   = (const int*)d_in[8];
    const float* Wl   = (const float*)d_in[9];
    const float* Wr   = (const float*)d_in[10];
    const float* bs   = (const float*)d_in[11];
    const float* Wout = (const float*)d_in[12];
    const float* bout = (const float*)d_in[13];
    float* out = (float*)d_out;

    const size_t NF = (size_t)NNODES * HID;   // 6.4M
    unsigned short* x0b = (unsigned short*)d_ws;
    unsigned short* xmb = x0b + NF;
    unsigned short* h1b = xmb + NF;
    unsigned short* h2b = h1b + NF;
    unsigned short* yb  = h2b + NF;
    unsigned short* S   = yb + NF;
    unsigned short* T   = S + NF;
    unsigned short* Wt  = T + NF;             // 6 * 16384 bf16
    unsigned short* WoT = Wt + 6 * 16384;     // 48 * 128 bf16
    int* rpa = (int*)(WoT + 48 * 128);
    int* rpb = rpa + (NNODES + 1);
    int* bcol2 = rpb + (NNODES + 1);

    const int gE = (NEDGES + 255) / 256;      // 1954
    const int gC = NNODES * HID / 4 / 256;    // 6250
    const int gG = NNODES / 16;               // 3125 (exact)
    const int gS2 = 2 * NNODES * 64 / 256;    // 25000

    prep_edges_kernel<<<3 * gE, 256, 0, stream>>>(arow, brow, bcol, id, rpa, rpb, bcol2, gE);
    prep_x_kernel<<<gC, 256, 0, stream>>>((const float4*)x0, id, mixr, (uint2*)x0b, (uint2*)xmb);
    prep_w_kernel<<<(6 * 16384 + 48 * 128) / 256, 256, 0, stream>>>(Wl, Wr, Wout, Wt, WoT);

    // y0 = x0 @ Wl0
    gemm_y_kernel<<<gG, 64, 0, stream>>>(x0b, Wt + 0 * 16384, yb);

    // ---- layer 0
    spmm2_kernel<<<gS2, 256, 0, stream>>>(yb, acol, aval, rpa, S, bcol2, bval, rpb, T);
    fused_layer_kernel<true><<<gG, 64, 0, stream>>>(
        x0b, xmb, Wt + 3 * 16384, Wt + 1 * 16384, S, T, bs, mixr,
        h1b, yb, xmb, nullptr, nullptr, nullptr);

    // ---- layer 1
    spmm2_kernel<<<gS2, 256, 0, stream>>>(yb, acol, aval, rpa, S, bcol2, bval, rpb, T);
    fused_layer_kernel<true><<<gG, 64, 0, stream>>>(
        h1b, xmb, Wt + 4 * 16384, Wt + 2 * 16384, S, T, bs + 128, mixr,
        h2b, yb, xmb, nullptr, nullptr, nullptr);

    // ---- layer 2 (+ head)
    spmm2_kernel<<<gS2, 256, 0, stream>>>(yb, acol, aval, rpa, S, bcol2, bval, rpb, T);
    fused_layer_kernel<false><<<gG, 64, 0, stream>>>(
        h2b, xmb, Wt + 5 * 16384, nullptr, S, T, bs + 256, mixr,
        nullptr, nullptr, nullptr, WoT, bout, out);
}